// Round 1
// baseline (8022.035 us; speedup 1.0000x reference)
//
#include <hip/hip_runtime.h>
#include <math.h>

#define L_ 4
#define D_ 512
#define H_ 8
#define T_ 1024
#define B_ 8
#define FF_ 2048
#define EC_ 1024
#define KW_ 31
#define DH_ 64
#define ROWS (B_*T_)   // 8192

// ---------------------------------------------------------------- LayerNorm
// one block (256 thr) per row of 512; float2 per thread
__global__ __launch_bounds__(256) void ln_kernel(const float* __restrict__ x,
    const float* __restrict__ g, const float* __restrict__ b, float* __restrict__ y)
{
  int row = blockIdx.x;
  int t = threadIdx.x;
  const float* xr = x + (size_t)row * D_;
  float2 v = *(const float2*)(xr + t * 2);
  float s  = v.x + v.y;
  float s2 = v.x * v.x + v.y * v.y;
#pragma unroll
  for (int off = 32; off; off >>= 1) {
    s  += __shfl_down(s,  off, 64);
    s2 += __shfl_down(s2, off, 64);
  }
  __shared__ float rs[4], rq[4];
  if ((t & 63) == 0) { rs[t >> 6] = s; rq[t >> 6] = s2; }
  __syncthreads();
  float S  = rs[0] + rs[1] + rs[2] + rs[3];
  float S2 = rq[0] + rq[1] + rq[2] + rq[3];
  float mean = S * (1.0f / D_);
  float var  = S2 * (1.0f / D_) - mean * mean;
  float r = 1.0f / sqrtf(var + 1e-5f);
  float2 gv = *(const float2*)(g + t * 2);
  float2 bv = *(const float2*)(b + t * 2);
  float2 o;
  o.x = (v.x - mean) * r * gv.x + bv.x;
  o.y = (v.y - mean) * r * gv.y + bv.y;
  *(float2*)(y + (size_t)row * D_ + t * 2) = o;
}

// ---------------------------------------------------------------- GEMM
// C[M,N] = epi(A[M,K] @ W[K,N] + bias).  EPI: 0=none, 1=silu, 2=residual (C=R+alpha*(..))
// 64x64 block tile, BK=16, 256 threads, 4x4 per thread, global->reg prefetch.
#define BM 64
#define BN 64
#define BKK 16
template<int EPI>
__global__ __launch_bounds__(256) void gemm_kernel(const float* __restrict__ A,
    const float* __restrict__ W, const float* __restrict__ bias,
    const float* __restrict__ R, float* __restrict__ C,
    int N, int K, float alpha)
{
  __shared__ float As[BKK][BM + 4];
  __shared__ float Ws[BKK][BN + 4];
  int t  = threadIdx.x;
  int tx = t & 15, ty = t >> 4;
  int row0 = blockIdx.y * BM, col0 = blockIdx.x * BN;
  int arow = t >> 2,  acol = (t & 3)  << 2;   // A tile: 64 rows x 16 cols, 1 float4/thread
  int wrow = t >> 4,  wcol = (t & 15) << 2;   // W tile: 16 rows x 64 cols
  const float* Ap = A + (size_t)(row0 + arow) * K + acol;
  const float* Wp = W + (size_t)wrow * N + col0 + wcol;

  float acc[4][4] = {};
  float4 av = *(const float4*)(Ap);
  float4 wv = *(const float4*)(Wp);

  for (int k0 = 0; k0 < K; k0 += BKK) {
    __syncthreads();
    As[acol + 0][arow] = av.x;
    As[acol + 1][arow] = av.y;
    As[acol + 2][arow] = av.z;
    As[acol + 3][arow] = av.w;
    *(float4*)&Ws[wrow][wcol] = wv;
    __syncthreads();
    if (k0 + BKK < K) {
      av = *(const float4*)(Ap + k0 + BKK);
      wv = *(const float4*)(Wp + (size_t)(k0 + BKK) * N);
    }
#pragma unroll
    for (int kk = 0; kk < BKK; ++kk) {
      float4 a4 = *(const float4*)&As[kk][ty << 2];
      float4 w4 = *(const float4*)&Ws[kk][tx << 2];
      float va[4] = {a4.x, a4.y, a4.z, a4.w};
      float vw[4] = {w4.x, w4.y, w4.z, w4.w};
#pragma unroll
      for (int i = 0; i < 4; ++i)
#pragma unroll
        for (int j = 0; j < 4; ++j)
          acc[i][j] = fmaf(va[i], vw[j], acc[i][j]);
    }
  }

  float4 bv4 = *(const float4*)(bias + col0 + (tx << 2));
  float bb[4] = {bv4.x, bv4.y, bv4.z, bv4.w};
#pragma unroll
  for (int i = 0; i < 4; ++i) {
    int r = row0 + (ty << 2) + i;
    float* op = C + (size_t)r * N + col0 + (tx << 2);
    float vals[4];
#pragma unroll
    for (int j = 0; j < 4; ++j) {
      float v = acc[i][j] + bb[j];
      if constexpr (EPI == 1) { float sg = 1.0f / (1.0f + expf(-v)); v = v * sg; }
      vals[j] = v;
    }
    if constexpr (EPI == 2) {
      float4 rv = *(const float4*)(R + (size_t)r * N + col0 + (tx << 2));
      vals[0] = rv.x + alpha * vals[0];
      vals[1] = rv.y + alpha * vals[1];
      vals[2] = rv.z + alpha * vals[2];
      vals[3] = rv.w + alpha * vals[3];
    }
    float4 o4 = {vals[0], vals[1], vals[2], vals[3]};
    *(float4*)op = o4;
  }
}

// ---------------------------------------------------------------- windowed attention
// grid (T/64, H, B), 256 threads. Q tile 64, key range [q0-32, q0+95].
__global__ __launch_bounds__(256) void attn_kernel(const float* __restrict__ QKV,
                                                   float* __restrict__ O)
{
  __shared__ float Qs[64][68];
  __shared__ float Ks[128][68];
  __shared__ float Vs[128][68];
  __shared__ float S[64][132];
  int qt = blockIdx.x, h = blockIdx.y, b = blockIdx.z;
  int t = threadIdx.x;
  int q0 = qt * 64;
  int jbase = q0 - 32;

  for (int i = t; i < 64 * 16; i += 256) {   // Q
    int r = i >> 4, c4 = (i & 15) << 2;
    const float* src = QKV + ((size_t)(b * T_ + q0 + r)) * 1536 + h * DH_ + c4;
    *(float4*)&Qs[r][c4] = *(const float4*)src;
  }
  for (int i = t; i < 128 * 16; i += 256) {  // K, V (zero-padded out of range)
    int r = i >> 4, c4 = (i & 15) << 2;
    int jg = jbase + r;
    float4 kv = {0, 0, 0, 0}, vv = {0, 0, 0, 0};
    if ((unsigned)jg < (unsigned)T_) {
      const float* kp = QKV + ((size_t)(b * T_ + jg)) * 1536 + 512 + h * DH_ + c4;
      kv = *(const float4*)kp;
      vv = *(const float4*)(kp + 512);
    }
    *(float4*)&Ks[r][c4] = kv;
    *(float4*)&Vs[r][c4] = vv;
  }
  __syncthreads();

  int q = t >> 2, l4 = t & 3;
  int qg = q0 + q;
  const float scale = 0.125f;  // DH^-0.5
  // scores: thread covers j = 4*jj + l4 (strided to avoid bank conflicts)
  for (int jj = 0; jj < 32; ++jj) {
    int j = (jj << 2) | l4;
    float acc = 0.f;
#pragma unroll
    for (int d = 0; d < 64; d += 4) {
      float4 qv = *(const float4*)&Qs[q][d];
      float4 kv = *(const float4*)&Ks[j][d];
      acc += qv.x * kv.x + qv.y * kv.y + qv.z * kv.z + qv.w * kv.w;
    }
    int jg = jbase + j;
    int dd = jg - qg;
    bool ok = ((unsigned)jg < (unsigned)T_) && (dd <= 32) && (dd >= -32);
    S[q][j] = ok ? acc * scale : -__builtin_inff();
  }
  __syncthreads();

  // softmax over 128 entries; 4 threads per row
  float mx = -__builtin_inff();
  for (int jj = 0; jj < 32; ++jj) mx = fmaxf(mx, S[q][(jj << 2) | l4]);
  mx = fmaxf(mx, __shfl_xor(mx, 1, 64));
  mx = fmaxf(mx, __shfl_xor(mx, 2, 64));
  float sum = 0.f;
  for (int jj = 0; jj < 32; ++jj) {
    int j = (jj << 2) | l4;
    float e = expf(S[q][j] - mx);
    S[q][j] = e;
    sum += e;
  }
  sum += __shfl_xor(sum, 1, 64);
  sum += __shfl_xor(sum, 2, 64);
  float inv = 1.0f / sum;
  __syncthreads();

  // PV: thread covers (q, 16 dims)
  int d0 = l4 << 4;
  float acc[16] = {};
  for (int j = 0; j < 128; ++j) {
    float p = S[q][j];
#pragma unroll
    for (int c = 0; c < 16; c += 4) {
      float4 v4 = *(const float4*)&Vs[j][d0 + c];
      acc[c + 0] = fmaf(p, v4.x, acc[c + 0]);
      acc[c + 1] = fmaf(p, v4.y, acc[c + 1]);
      acc[c + 2] = fmaf(p, v4.z, acc[c + 2]);
      acc[c + 3] = fmaf(p, v4.w, acc[c + 3]);
    }
  }
  float* op = O + ((size_t)(b * T_ + qg)) * D_ + h * DH_ + d0;
#pragma unroll
  for (int c = 0; c < 16; c += 4) {
    float4 o4 = {acc[c] * inv, acc[c + 1] * inv, acc[c + 2] * inv, acc[c + 3] * inv};
    *(float4*)(op + c) = o4;
  }
}

// ---------------------------------------------------------------- GLU
__global__ __launch_bounds__(256) void glu_kernel(const float* __restrict__ P,
                                                  float* __restrict__ G)
{
  int idx = blockIdx.x * 256 + threadIdx.x;  // float4 index over [ROWS][EC]
  int row = idx >> 8;
  int c4  = (idx & 255) << 2;
  const float* p = P + (size_t)row * (2 * EC_);
  float4 a = *(const float4*)(p + c4);
  float4 g = *(const float4*)(p + EC_ + c4);
  float4 o;
  o.x = a.x * (1.0f / (1.0f + expf(-g.x)));
  o.y = a.y * (1.0f / (1.0f + expf(-g.y)));
  o.z = a.z * (1.0f / (1.0f + expf(-g.z)));
  o.w = a.w * (1.0f / (1.0f + expf(-g.w)));
  *(float4*)(G + (size_t)row * EC_ + c4) = o;
}

// ---------------------------------------------------------------- depthwise conv (k=31, pad 15) over T
// layout [B,T,EC]; thread per element
__global__ __launch_bounds__(256) void dwconv_kernel(const float* __restrict__ X,
    const float* __restrict__ w, const float* __restrict__ bias, float* __restrict__ Y)
{
  int idx = blockIdx.x * 256 + threadIdx.x;
  int e  = idx & (EC_ - 1);
  int bt = idx >> 10;
  int tt = bt & (T_ - 1);
  int b  = bt >> 10;
  float acc = bias[e];
  const float* xp = X + (size_t)b * T_ * EC_;
#pragma unroll
  for (int k = 0; k < KW_; ++k) {
    int tj = tt + k - 15;
    if ((unsigned)tj < (unsigned)T_)
      acc = fmaf(xp[((size_t)tj << 10) + e], w[e * KW_ + k], acc);
  }
  Y[idx] = acc;
}

// ---------------------------------------------------------------- GroupNorm (1 group, per sample over T*EC)
__global__ __launch_bounds__(256) void gn_reduce_kernel(const float* __restrict__ X,
                                                        float* __restrict__ partial)
{
  int b = blockIdx.y, blk = blockIdx.x;  // 128 blocks/sample
  const float* p = X + (size_t)b * (T_ * EC_) + (size_t)blk * 8192;
  int t = threadIdx.x;
  float s = 0.f, s2 = 0.f;
#pragma unroll
  for (int i = 0; i < 8; ++i) {
    float4 v = *(const float4*)(p + (size_t)((i << 8) + t) * 4);
    s  += v.x + v.y + v.z + v.w;
    s2 += v.x * v.x + v.y * v.y + v.z * v.z + v.w * v.w;
  }
#pragma unroll
  for (int off = 32; off; off >>= 1) {
    s  += __shfl_down(s,  off, 64);
    s2 += __shfl_down(s2, off, 64);
  }
  __shared__ float rs[4], rq[4];
  if ((t & 63) == 0) { rs[t >> 6] = s; rq[t >> 6] = s2; }
  __syncthreads();
  if (t == 0) {
    partial[(b * 128 + blk) * 2]     = rs[0] + rs[1] + rs[2] + rs[3];
    partial[(b * 128 + blk) * 2 + 1] = rq[0] + rq[1] + rq[2] + rq[3];
  }
}

__global__ __launch_bounds__(128) void gn_stats_kernel(const float* __restrict__ partial,
                                                       float* __restrict__ stats)
{
  int b = blockIdx.x, t = threadIdx.x;
  float s  = partial[(b * 128 + t) * 2];
  float s2 = partial[(b * 128 + t) * 2 + 1];
#pragma unroll
  for (int off = 32; off; off >>= 1) {
    s  += __shfl_down(s,  off, 64);
    s2 += __shfl_down(s2, off, 64);
  }
  __shared__ float rs[2], rq[2];
  if ((t & 63) == 0) { rs[t >> 6] = s; rq[t >> 6] = s2; }
  __syncthreads();
  if (t == 0) {
    float S = rs[0] + rs[1], S2 = rq[0] + rq[1];
    const float n = (float)(T_ * EC_);
    float mean = S / n;
    float var  = S2 / n - mean * mean;
    stats[b * 2]     = mean;
    stats[b * 2 + 1] = 1.0f / sqrtf(var + 1e-5f);
  }
}

__global__ __launch_bounds__(256) void gn_apply_kernel(float* __restrict__ X,
    const float* __restrict__ stats, const float* __restrict__ g, const float* __restrict__ bb)
{
  int idx = blockIdx.x * 256 + threadIdx.x;  // float4 index over [B,T,EC]
  int e4 = (idx & 255) << 2;
  int bt = idx >> 8;
  int b  = bt >> 10;
  float mean = stats[b * 2], rstd = stats[b * 2 + 1];
  float4 v  = *(const float4*)(X + (size_t)idx * 4);
  float4 gv = *(const float4*)(g + e4);
  float4 bv = *(const float4*)(bb + e4);
  float vv[4] = {v.x, v.y, v.z, v.w};
  float gg[4] = {gv.x, gv.y, gv.z, gv.w};
  float bbv[4] = {bv.x, bv.y, bv.z, bv.w};
  float o[4];
#pragma unroll
  for (int j = 0; j < 4; ++j) {
    float u = (vv[j] - mean) * rstd * gg[j] + bbv[j];
    o[j] = u * (1.0f / (1.0f + expf(-u)));   // silu
  }
  float4 o4 = {o[0], o[1], o[2], o[3]};
  *(float4*)(X + (size_t)idx * 4) = o4;
}

// ---------------------------------------------------------------- launch
extern "C" void kernel_launch(void* const* d_in, const int* in_sizes, int n_in,
                              void* d_out, int out_size, void* d_ws, size_t ws_size,
                              hipStream_t stream)
{
  const float* in_x      = (const float*)d_in[0];
  const float* ffn1_ln_g = (const float*)d_in[1];
  const float* ffn1_ln_b = (const float*)d_in[2];
  const float* ffn1_w1   = (const float*)d_in[3];
  const float* ffn1_b1   = (const float*)d_in[4];
  const float* ffn1_w2   = (const float*)d_in[5];
  const float* ffn1_b2   = (const float*)d_in[6];
  const float* attn_ln_g = (const float*)d_in[7];
  const float* attn_ln_b = (const float*)d_in[8];
  const float* qkv_w     = (const float*)d_in[9];
  const float* qkv_b     = (const float*)d_in[10];
  const float* outp_w    = (const float*)d_in[11];
  const float* outp_b    = (const float*)d_in[12];
  const float* conv_ln_g = (const float*)d_in[13];
  const float* conv_ln_b = (const float*)d_in[14];
  const float* pw1_w     = (const float*)d_in[15];
  const float* pw1_b     = (const float*)d_in[16];
  const float* dw_w      = (const float*)d_in[17];
  const float* dw_b      = (const float*)d_in[18];
  const float* gn_g      = (const float*)d_in[19];
  const float* gn_b      = (const float*)d_in[20];
  const float* pw2_w     = (const float*)d_in[21];
  const float* pw2_b     = (const float*)d_in[22];
  const float* ffn2_ln_g = (const float*)d_in[23];
  const float* ffn2_ln_b = (const float*)d_in[24];
  const float* ffn2_w1   = (const float*)d_in[25];
  const float* ffn2_b1   = (const float*)d_in[26];
  const float* ffn2_w2   = (const float*)d_in[27];
  const float* ffn2_b2   = (const float*)d_in[28];
  const float* blk_ln_g  = (const float*)d_in[29];
  const float* blk_ln_b  = (const float*)d_in[30];
  const float* fin_ln_g  = (const float*)d_in[31];
  const float* fin_ln_b  = (const float*)d_in[32];

  float* ws   = (float*)d_ws;
  float* x    = ws;                                // 4M floats
  float* lnb  = x    + (size_t)ROWS * D_;          // 4M
  float* big1 = lnb  + (size_t)ROWS * D_;          // 16.78M (FFN inner / QKV / pw1)
  float* big2 = big1 + (size_t)ROWS * FF_;         // 8.39M  (GLU out / attn O)
  float* big3 = big2 + (size_t)ROWS * EC_;         // 8.39M  (conv out)
  float* red  = big3 + (size_t)ROWS * EC_;         // 2048 partials + 16 stats

  hipMemcpyAsync(x, in_x, sizeof(float) * (size_t)ROWS * D_,
                 hipMemcpyDeviceToDevice, stream);

  dim3 blk256(256);
  for (int l = 0; l < L_; ++l) {
    // ---- FFN1 (half residual) ----
    ln_kernel<<<ROWS, blk256, 0, stream>>>(x, ffn1_ln_g + l * D_, ffn1_ln_b + l * D_, lnb);
    gemm_kernel<1><<<dim3(FF_ / BN, ROWS / BM), blk256, 0, stream>>>(
        lnb, ffn1_w1 + (size_t)l * D_ * FF_, ffn1_b1 + l * FF_, nullptr, big1, FF_, D_, 0.f);
    gemm_kernel<2><<<dim3(D_ / BN, ROWS / BM), blk256, 0, stream>>>(
        big1, ffn1_w2 + (size_t)l * FF_ * D_, ffn1_b2 + l * D_, x, x, D_, FF_, 0.5f);

    // ---- local windowed MHSA ----
    ln_kernel<<<ROWS, blk256, 0, stream>>>(x, attn_ln_g + l * D_, attn_ln_b + l * D_, lnb);
    gemm_kernel<0><<<dim3(1536 / BN, ROWS / BM), blk256, 0, stream>>>(
        lnb, qkv_w + (size_t)l * D_ * 1536, qkv_b + l * 1536, nullptr, big1, 1536, D_, 0.f);
    attn_kernel<<<dim3(T_ / 64, H_, B_), blk256, 0, stream>>>(big1, big2);
    gemm_kernel<2><<<dim3(D_ / BN, ROWS / BM), blk256, 0, stream>>>(
        big2, outp_w + (size_t)l * D_ * D_, outp_b + l * D_, x, x, D_, D_, 1.0f);

    // ---- conv module ----
    ln_kernel<<<ROWS, blk256, 0, stream>>>(x, conv_ln_g + l * D_, conv_ln_b + l * D_, lnb);
    gemm_kernel<0><<<dim3(2048 / BN, ROWS / BM), blk256, 0, stream>>>(
        lnb, pw1_w + (size_t)l * D_ * 2048, pw1_b + l * 2048, nullptr, big1, 2048, D_, 0.f);
    glu_kernel<<<(ROWS * EC_ / 4) / 256, blk256, 0, stream>>>(big1, big2);
    dwconv_kernel<<<(ROWS * EC_) / 256, blk256, 0, stream>>>(
        big2, dw_w + (size_t)l * EC_ * KW_, dw_b + l * EC_, big3);
    gn_reduce_kernel<<<dim3(128, B_), blk256, 0, stream>>>(big3, red);
    gn_stats_kernel<<<B_, 128, 0, stream>>>(red, red + 2048);
    gn_apply_kernel<<<(ROWS * EC_ / 4) / 256, blk256, 0, stream>>>(
        big3, red + 2048, gn_g + l * EC_, gn_b + l * EC_);
    gemm_kernel<2><<<dim3(D_ / BN, ROWS / BM), blk256, 0, stream>>>(
        big3, pw2_w + (size_t)l * EC_ * D_, pw2_b + l * D_, x, x, D_, EC_, 1.0f);

    // ---- FFN2 (half residual) ----
    ln_kernel<<<ROWS, blk256, 0, stream>>>(x, ffn2_ln_g + l * D_, ffn2_ln_b + l * D_, lnb);
    gemm_kernel<1><<<dim3(FF_ / BN, ROWS / BM), blk256, 0, stream>>>(
        lnb, ffn2_w1 + (size_t)l * D_ * FF_, ffn2_b1 + l * FF_, nullptr, big1, FF_, D_, 0.f);
    gemm_kernel<2><<<dim3(D_ / BN, ROWS / BM), blk256, 0, stream>>>(
        big1, ffn2_w2 + (size_t)l * FF_ * D_, ffn2_b2 + l * D_, x, x, D_, FF_, 0.5f);

    // ---- per-block final LN (in place) ----
    ln_kernel<<<ROWS, blk256, 0, stream>>>(x, blk_ln_g + l * D_, blk_ln_b + l * D_, x);
  }

  ln_kernel<<<ROWS, blk256, 0, stream>>>(x, fin_ln_g, fin_ln_b, (float*)d_out);
}

// Round 2
// 6281.329 us; speedup vs baseline: 1.2771x; 1.2771x over previous
//
#include <hip/hip_runtime.h>
#include <math.h>

#define L_ 4
#define D_ 512
#define H_ 8
#define T_ 1024
#define B_ 8
#define FF_ 2048
#define EC_ 1024
#define KW_ 31
#define DH_ 64
#define ROWS (B_*T_)   // 8192

// ---------------------------------------------------------------- LayerNorm
__global__ __launch_bounds__(256) void ln_kernel(const float* __restrict__ x,
    const float* __restrict__ g, const float* __restrict__ b, float* __restrict__ y)
{
  int row = blockIdx.x;
  int t = threadIdx.x;
  const float* xr = x + (size_t)row * D_;
  float2 v = *(const float2*)(xr + t * 2);
  float s  = v.x + v.y;
  float s2 = v.x * v.x + v.y * v.y;
#pragma unroll
  for (int off = 32; off; off >>= 1) {
    s  += __shfl_down(s,  off, 64);
    s2 += __shfl_down(s2, off, 64);
  }
  __shared__ float rs[4], rq[4];
  if ((t & 63) == 0) { rs[t >> 6] = s; rq[t >> 6] = s2; }
  __syncthreads();
  float S  = rs[0] + rs[1] + rs[2] + rs[3];
  float S2 = rq[0] + rq[1] + rq[2] + rq[3];
  float mean = S * (1.0f / D_);
  float var  = S2 * (1.0f / D_) - mean * mean;
  float r = 1.0f / sqrtf(var + 1e-5f);
  float2 gv = *(const float2*)(g + t * 2);
  float2 bv = *(const float2*)(b + t * 2);
  float2 o;
  o.x = (v.x - mean) * r * gv.x + bv.x;
  o.y = (v.y - mean) * r * gv.y + bv.y;
  *(float2*)(y + (size_t)row * D_ + t * 2) = o;
}

// ---------------------------------------------------------------- GEMM
// C[M,N] = epi(A[M,K] @ W[K,N] + bias). EPI: 0=none 1=silu 2=residual
// BM=128, BK=16, TM=8. (BN_,TN_) = (128,8) or (64,4). 256 threads.
template<int EPI, int BN_, int TN_>
__global__ __launch_bounds__(256) void gemm_kernel(const float* __restrict__ A,
    const float* __restrict__ W, const float* __restrict__ bias,
    const float* __restrict__ R, float* __restrict__ C,
    int N, int K, float alpha)
{
  __shared__ float As[16][132];
  __shared__ float Ws[16][BN_ + 4];
  int t  = threadIdx.x;
  int tx = t & 15, ty = t >> 4;
  int row0 = blockIdx.y * 128, col0 = blockIdx.x * BN_;

  int arow = t >> 1;             // 0..127
  int acol = (t & 1) * 8;        // 0 or 8
  const float* Ap = A + (size_t)(row0 + arow) * K + acol;
  constexpr int WPT = BN_ / 16;  // 8 or 4 floats per thread
  int wrow = t >> 4;             // 0..15
  int wcol = (t & 15) * WPT;
  const float* Wp = W + (size_t)wrow * N + col0 + wcol;

  float acc[8][TN_] = {};
  float4 a0 = *(const float4*)(Ap);
  float4 a1 = *(const float4*)(Ap + 4);
  float4 w0 = *(const float4*)(Wp);
  float4 w1 = {};
  if constexpr (WPT == 8) w1 = *(const float4*)(Wp + 4);

  for (int k0 = 0; k0 < K; k0 += 16) {
    __syncthreads();
#pragma unroll
    for (int i = 0; i < 4; ++i) As[acol + i][arow]     = ((const float*)&a0)[i];
#pragma unroll
    for (int i = 0; i < 4; ++i) As[acol + 4 + i][arow] = ((const float*)&a1)[i];
    *(float4*)&Ws[wrow][wcol] = w0;
    if constexpr (WPT == 8) *(float4*)&Ws[wrow][wcol + 4] = w1;
    __syncthreads();
    if (k0 + 16 < K) {
      a0 = *(const float4*)(Ap + k0 + 16);
      a1 = *(const float4*)(Ap + k0 + 20);
      w0 = *(const float4*)(Wp + (size_t)(k0 + 16) * N);
      if constexpr (WPT == 8) w1 = *(const float4*)(Wp + (size_t)(k0 + 16) * N + 4);
    }
#pragma unroll
    for (int kk = 0; kk < 16; ++kk) {
      float a8[8];
      *(float4*)&a8[0] = *(const float4*)&As[kk][ty * 8];
      *(float4*)&a8[4] = *(const float4*)&As[kk][ty * 8 + 4];
      float wv[TN_];
      *(float4*)&wv[0] = *(const float4*)&Ws[kk][tx * TN_];
      if constexpr (TN_ == 8) *(float4*)&wv[4] = *(const float4*)&Ws[kk][tx * TN_ + 4];
#pragma unroll
      for (int i = 0; i < 8; ++i)
#pragma unroll
        for (int j = 0; j < TN_; ++j)
          acc[i][j] = fmaf(a8[i], wv[j], acc[i][j]);
    }
  }

  float bb[TN_];
  *(float4*)&bb[0] = *(const float4*)(bias + col0 + tx * TN_);
  if constexpr (TN_ == 8) *(float4*)&bb[4] = *(const float4*)(bias + col0 + tx * TN_ + 4);

#pragma unroll
  for (int i = 0; i < 8; ++i) {
    int r = row0 + ty * 8 + i;
    float* op = C + (size_t)r * N + col0 + tx * TN_;
    float vals[TN_];
#pragma unroll
    for (int j = 0; j < TN_; ++j) {
      float v = acc[i][j] + bb[j];
      if constexpr (EPI == 1) { float sg = 1.0f / (1.0f + expf(-v)); v = v * sg; }
      vals[j] = v;
    }
    if constexpr (EPI == 2) {
      const float* rp = R + (size_t)r * N + col0 + tx * TN_;
#pragma unroll
      for (int j = 0; j < TN_; j += 4) {
        float4 rv = *(const float4*)(rp + j);
        vals[j + 0] = rv.x + alpha * vals[j + 0];
        vals[j + 1] = rv.y + alpha * vals[j + 1];
        vals[j + 2] = rv.z + alpha * vals[j + 2];
        vals[j + 3] = rv.w + alpha * vals[j + 3];
      }
    }
#pragma unroll
    for (int j = 0; j < TN_; j += 4) {
      float4 o4 = {vals[j], vals[j + 1], vals[j + 2], vals[j + 3]};
      *(float4*)(op + j) = o4;
    }
  }
}

// ---------------------------------------------------------------- windowed attention
__global__ __launch_bounds__(256) void attn_kernel(const float* __restrict__ QKV,
                                                   float* __restrict__ O)
{
  __shared__ float Qs[64][68];
  __shared__ float Ks[128][68];
  __shared__ float Vs[128][68];
  __shared__ float S[64][132];
  int qt = blockIdx.x, h = blockIdx.y, b = blockIdx.z;
  int t = threadIdx.x;
  int q0 = qt * 64;
  int jbase = q0 - 32;

  for (int i = t; i < 64 * 16; i += 256) {
    int r = i >> 4, c4 = (i & 15) << 2;
    const float* src = QKV + ((size_t)(b * T_ + q0 + r)) * 1536 + h * DH_ + c4;
    *(float4*)&Qs[r][c4] = *(const float4*)src;
  }
  for (int i = t; i < 128 * 16; i += 256) {
    int r = i >> 4, c4 = (i & 15) << 2;
    int jg = jbase + r;
    float4 kv = {0, 0, 0, 0}, vv = {0, 0, 0, 0};
    if ((unsigned)jg < (unsigned)T_) {
      const float* kp = QKV + ((size_t)(b * T_ + jg)) * 1536 + 512 + h * DH_ + c4;
      kv = *(const float4*)kp;
      vv = *(const float4*)(kp + 512);
    }
    *(float4*)&Ks[r][c4] = kv;
    *(float4*)&Vs[r][c4] = vv;
  }
  __syncthreads();

  int q = t >> 2, l4 = t & 3;
  int qg = q0 + q;
  const float scale = 0.125f;
  for (int jj = 0; jj < 32; ++jj) {
    int j = (jj << 2) | l4;
    float acc = 0.f;
#pragma unroll
    for (int d = 0; d < 64; d += 4) {
      float4 qv = *(const float4*)&Qs[q][d];
      float4 kv = *(const float4*)&Ks[j][d];
      acc += qv.x * kv.x + qv.y * kv.y + qv.z * kv.z + qv.w * kv.w;
    }
    int jg = jbase + j;
    int dd = jg - qg;
    bool ok = ((unsigned)jg < (unsigned)T_) && (dd <= 32) && (dd >= -32);
    S[q][j] = ok ? acc * scale : -__builtin_inff();
  }
  __syncthreads();

  float mx = -__builtin_inff();
  for (int jj = 0; jj < 32; ++jj) mx = fmaxf(mx, S[q][(jj << 2) | l4]);
  mx = fmaxf(mx, __shfl_xor(mx, 1, 64));
  mx = fmaxf(mx, __shfl_xor(mx, 2, 64));
  float sum = 0.f;
  for (int jj = 0; jj < 32; ++jj) {
    int j = (jj << 2) | l4;
    float e = expf(S[q][j] - mx);
    S[q][j] = e;
    sum += e;
  }
  sum += __shfl_xor(sum, 1, 64);
  sum += __shfl_xor(sum, 2, 64);
  float inv = 1.0f / sum;
  __syncthreads();

  int d0 = l4 << 4;
  float acc[16] = {};
  for (int j = 0; j < 128; ++j) {
    float p = S[q][j];
#pragma unroll
    for (int c = 0; c < 16; c += 4) {
      float4 v4 = *(const float4*)&Vs[j][d0 + c];
      acc[c + 0] = fmaf(p, v4.x, acc[c + 0]);
      acc[c + 1] = fmaf(p, v4.y, acc[c + 1]);
      acc[c + 2] = fmaf(p, v4.z, acc[c + 2]);
      acc[c + 3] = fmaf(p, v4.w, acc[c + 3]);
    }
  }
  float* op = O + ((size_t)(b * T_ + qg)) * D_ + h * DH_ + d0;
#pragma unroll
  for (int c = 0; c < 16; c += 4) {
    float4 o4 = {acc[c] * inv, acc[c + 1] * inv, acc[c + 2] * inv, acc[c + 3] * inv};
    *(float4*)(op + c) = o4;
  }
}

// ---------------------------------------------------------------- GLU
__global__ __launch_bounds__(256) void glu_kernel(const float* __restrict__ P,
                                                  float* __restrict__ G)
{
  int idx = blockIdx.x * 256 + threadIdx.x;
  int row = idx >> 8;
  int c4  = (idx & 255) << 2;
  const float* p = P + (size_t)row * (2 * EC_);
  float4 a = *(const float4*)(p + c4);
  float4 g = *(const float4*)(p + EC_ + c4);
  float4 o;
  o.x = a.x * (1.0f / (1.0f + expf(-g.x)));
  o.y = a.y * (1.0f / (1.0f + expf(-g.y)));
  o.z = a.z * (1.0f / (1.0f + expf(-g.z)));
  o.w = a.w * (1.0f / (1.0f + expf(-g.w)));
  *(float4*)(G + (size_t)row * EC_ + c4) = o;
}

// ---------------------------------------------------------------- depthwise conv k=31 pad=15
// input-stationary: thread owns (b, e, 16 consecutive t); 31 weights in regs.
#define TT_ 16
__global__ __launch_bounds__(256) void dwconv_kernel(const float* __restrict__ X,
    const float* __restrict__ w, const float* __restrict__ bias, float* __restrict__ Y)
{
  int t = threadIdx.x;
  int gid = blockIdx.x;           // B * (T/TT_) * (EC/256) = 8*64*4 = 2048
  int ecb = gid & 3;
  int tt  = (gid >> 2) & 63;
  int b   = gid >> 8;
  int e  = ecb * 256 + t;
  int t0 = tt * TT_;
  const float* xp = X + (size_t)b * T_ * EC_ + e;

  float wr[KW_];
#pragma unroll
  for (int k = 0; k < KW_; ++k) wr[k] = w[e * KW_ + k];
  float out[TT_];
  float bv = bias[e];
#pragma unroll
  for (int i = 0; i < TT_; ++i) out[i] = bv;

#pragma unroll
  for (int j = 0; j < TT_ + KW_ - 1; ++j) {
    int tj = t0 - 15 + j;
    float xv = ((unsigned)tj < (unsigned)T_) ? xp[(size_t)tj * EC_] : 0.f;
#pragma unroll
    for (int i = 0; i < TT_; ++i) {
      int k = j - i;
      if (k >= 0 && k < KW_) out[i] = fmaf(xv, wr[k], out[i]);
    }
  }
  float* yp = Y + ((size_t)b * T_ + t0) * EC_ + e;
#pragma unroll
  for (int i = 0; i < TT_; ++i) yp[(size_t)i * EC_] = out[i];
}

// ---------------------------------------------------------------- GroupNorm
__global__ __launch_bounds__(256) void gn_reduce_kernel(const float* __restrict__ X,
                                                        float* __restrict__ partial)
{
  int b = blockIdx.y, blk = blockIdx.x;
  const float* p = X + (size_t)b * (T_ * EC_) + (size_t)blk * 8192;
  int t = threadIdx.x;
  float s = 0.f, s2 = 0.f;
#pragma unroll
  for (int i = 0; i < 8; ++i) {
    float4 v = *(const float4*)(p + (size_t)((i << 8) + t) * 4);
    s  += v.x + v.y + v.z + v.w;
    s2 += v.x * v.x + v.y * v.y + v.z * v.z + v.w * v.w;
  }
#pragma unroll
  for (int off = 32; off; off >>= 1) {
    s  += __shfl_down(s,  off, 64);
    s2 += __shfl_down(s2, off, 64);
  }
  __shared__ float rs[4], rq[4];
  if ((t & 63) == 0) { rs[t >> 6] = s; rq[t >> 6] = s2; }
  __syncthreads();
  if (t == 0) {
    partial[(b * 128 + blk) * 2]     = rs[0] + rs[1] + rs[2] + rs[3];
    partial[(b * 128 + blk) * 2 + 1] = rq[0] + rq[1] + rq[2] + rq[3];
  }
}

__global__ __launch_bounds__(128) void gn_stats_kernel(const float* __restrict__ partial,
                                                       float* __restrict__ stats)
{
  int b = blockIdx.x, t = threadIdx.x;
  float s  = partial[(b * 128 + t) * 2];
  float s2 = partial[(b * 128 + t) * 2 + 1];
#pragma unroll
  for (int off = 32; off; off >>= 1) {
    s  += __shfl_down(s,  off, 64);
    s2 += __shfl_down(s2, off, 64);
  }
  __shared__ float rs[2], rq[2];
  if ((t & 63) == 0) { rs[t >> 6] = s; rq[t >> 6] = s2; }
  __syncthreads();
  if (t == 0) {
    float S = rs[0] + rs[1], S2 = rq[0] + rq[1];
    const float n = (float)(T_ * EC_);
    float mean = S / n;
    float var  = S2 / n - mean * mean;
    stats[b * 2]     = mean;
    stats[b * 2 + 1] = 1.0f / sqrtf(var + 1e-5f);
  }
}

__global__ __launch_bounds__(256) void gn_apply_kernel(float* __restrict__ X,
    const float* __restrict__ stats, const float* __restrict__ g, const float* __restrict__ bb)
{
  int idx = blockIdx.x * 256 + threadIdx.x;
  int e4 = (idx & 255) << 2;
  int bt = idx >> 8;
  int b  = bt >> 10;
  float mean = stats[b * 2], rstd = stats[b * 2 + 1];
  float4 v  = *(const float4*)(X + (size_t)idx * 4);
  float4 gv = *(const float4*)(g + e4);
  float4 bv = *(const float4*)(bb + e4);
  float vv[4] = {v.x, v.y, v.z, v.w};
  float gg[4] = {gv.x, gv.y, gv.z, gv.w};
  float bbv[4] = {bv.x, bv.y, bv.z, bv.w};
  float o[4];
#pragma unroll
  for (int j = 0; j < 4; ++j) {
    float u = (vv[j] - mean) * rstd * gg[j] + bbv[j];
    o[j] = u * (1.0f / (1.0f + expf(-u)));
  }
  float4 o4 = {o[0], o[1], o[2], o[3]};
  *(float4*)(X + (size_t)idx * 4) = o4;
}

// ---------------------------------------------------------------- launch
extern "C" void kernel_launch(void* const* d_in, const int* in_sizes, int n_in,
                              void* d_out, int out_size, void* d_ws, size_t ws_size,
                              hipStream_t stream)
{
  const float* in_x      = (const float*)d_in[0];
  const float* ffn1_ln_g = (const float*)d_in[1];
  const float* ffn1_ln_b = (const float*)d_in[2];
  const float* ffn1_w1   = (const float*)d_in[3];
  const float* ffn1_b1   = (const float*)d_in[4];
  const float* ffn1_w2   = (const float*)d_in[5];
  const float* ffn1_b2   = (const float*)d_in[6];
  const float* attn_ln_g = (const float*)d_in[7];
  const float* attn_ln_b = (const float*)d_in[8];
  const float* qkv_w     = (const float*)d_in[9];
  const float* qkv_b     = (const float*)d_in[10];
  const float* outp_w    = (const float*)d_in[11];
  const float* outp_b    = (const float*)d_in[12];
  const float* conv_ln_g = (const float*)d_in[13];
  const float* conv_ln_b = (const float*)d_in[14];
  const float* pw1_w     = (const float*)d_in[15];
  const float* pw1_b     = (const float*)d_in[16];
  const float* dw_w      = (const float*)d_in[17];
  const float* dw_b      = (const float*)d_in[18];
  const float* gn_g      = (const float*)d_in[19];
  const float* gn_b      = (const float*)d_in[20];
  const float* pw2_w     = (const float*)d_in[21];
  const float* pw2_b     = (const float*)d_in[22];
  const float* ffn2_ln_g = (const float*)d_in[23];
  const float* ffn2_ln_b = (const float*)d_in[24];
  const float* ffn2_w1   = (const float*)d_in[25];
  const float* ffn2_b1   = (const float*)d_in[26];
  const float* ffn2_w2   = (const float*)d_in[27];
  const float* ffn2_b2   = (const float*)d_in[28];
  const float* blk_ln_g  = (const float*)d_in[29];
  const float* blk_ln_b  = (const float*)d_in[30];
  const float* fin_ln_g  = (const float*)d_in[31];
  const float* fin_ln_b  = (const float*)d_in[32];

  float* ws   = (float*)d_ws;
  float* x    = ws;
  float* lnb  = x    + (size_t)ROWS * D_;
  float* big1 = lnb  + (size_t)ROWS * D_;
  float* big2 = big1 + (size_t)ROWS * FF_;
  float* big3 = big2 + (size_t)ROWS * EC_;
  float* red  = big3 + (size_t)ROWS * EC_;

  hipMemcpyAsync(x, in_x, sizeof(float) * (size_t)ROWS * D_,
                 hipMemcpyDeviceToDevice, stream);

  dim3 blk256(256);
  for (int l = 0; l < L_; ++l) {
    // ---- FFN1 ----
    ln_kernel<<<ROWS, blk256, 0, stream>>>(x, ffn1_ln_g + l * D_, ffn1_ln_b + l * D_, lnb);
    gemm_kernel<1, 128, 8><<<dim3(FF_ / 128, ROWS / 128), blk256, 0, stream>>>(
        lnb, ffn1_w1 + (size_t)l * D_ * FF_, ffn1_b1 + l * FF_, nullptr, big1, FF_, D_, 0.f);
    gemm_kernel<2, 64, 4><<<dim3(D_ / 64, ROWS / 128), blk256, 0, stream>>>(
        big1, ffn1_w2 + (size_t)l * FF_ * D_, ffn1_b2 + l * D_, x, x, D_, FF_, 0.5f);

    // ---- local windowed MHSA ----
    ln_kernel<<<ROWS, blk256, 0, stream>>>(x, attn_ln_g + l * D_, attn_ln_b + l * D_, lnb);
    gemm_kernel<0, 128, 8><<<dim3(1536 / 128, ROWS / 128), blk256, 0, stream>>>(
        lnb, qkv_w + (size_t)l * D_ * 1536, qkv_b + l * 1536, nullptr, big1, 1536, D_, 0.f);
    attn_kernel<<<dim3(T_ / 64, H_, B_), blk256, 0, stream>>>(big1, big2);
    gemm_kernel<2, 64, 4><<<dim3(D_ / 64, ROWS / 128), blk256, 0, stream>>>(
        big2, outp_w + (size_t)l * D_ * D_, outp_b + l * D_, x, x, D_, D_, 1.0f);

    // ---- conv module ----
    ln_kernel<<<ROWS, blk256, 0, stream>>>(x, conv_ln_g + l * D_, conv_ln_b + l * D_, lnb);
    gemm_kernel<0, 128, 8><<<dim3(2048 / 128, ROWS / 128), blk256, 0, stream>>>(
        lnb, pw1_w + (size_t)l * D_ * 2048, pw1_b + l * 2048, nullptr, big1, 2048, D_, 0.f);
    glu_kernel<<<(ROWS * EC_ / 4) / 256, blk256, 0, stream>>>(big1, big2);
    dwconv_kernel<<<B_ * (T_ / TT_) * (EC_ / 256), blk256, 0, stream>>>(
        big2, dw_w + (size_t)l * EC_ * KW_, dw_b + l * EC_, big3);
    gn_reduce_kernel<<<dim3(128, B_), blk256, 0, stream>>>(big3, red);
    gn_stats_kernel<<<B_, 128, 0, stream>>>(red, red + 2048);
    gn_apply_kernel<<<(ROWS * EC_ / 4) / 256, blk256, 0, stream>>>(
        big3, red + 2048, gn_g + l * EC_, gn_b + l * EC_);
    gemm_kernel<2, 64, 4><<<dim3(D_ / 64, ROWS / 128), blk256, 0, stream>>>(
        big3, pw2_w + (size_t)l * EC_ * D_, pw2_b + l * D_, x, x, D_, EC_, 1.0f);

    // ---- FFN2 ----
    ln_kernel<<<ROWS, blk256, 0, stream>>>(x, ffn2_ln_g + l * D_, ffn2_ln_b + l * D_, lnb);
    gemm_kernel<1, 128, 8><<<dim3(FF_ / 128, ROWS / 128), blk256, 0, stream>>>(
        lnb, ffn2_w1 + (size_t)l * D_ * FF_, ffn2_b1 + l * FF_, nullptr, big1, FF_, D_, 0.f);
    gemm_kernel<2, 64, 4><<<dim3(D_ / 64, ROWS / 128), blk256, 0, stream>>>(
        big1, ffn2_w2 + (size_t)l * FF_ * D_, ffn2_b2 + l * D_, x, x, D_, FF_, 0.5f);

    // ---- per-block final LN ----
    ln_kernel<<<ROWS, blk256, 0, stream>>>(x, blk_ln_g + l * D_, blk_ln_b + l * D_, x);
  }

  ln_kernel<<<ROWS, blk256, 0, stream>>>(x, fin_ln_g, fin_ln_b, (float*)d_out);
}

// Round 3
// 1982.884 us; speedup vs baseline: 4.0456x; 3.1678x over previous
//
#include <hip/hip_runtime.h>
#include <math.h>

#define L_ 4
#define D_ 512
#define H_ 8
#define T_ 1024
#define B_ 8
#define FF_ 2048
#define EC_ 1024
#define KW_ 31
#define DH_ 64
#define ROWS (B_*T_)   // 8192

typedef __attribute__((ext_vector_type(8))) short short8;
typedef __attribute__((ext_vector_type(4))) float f32x4;
typedef __attribute__((ext_vector_type(2))) unsigned short ushort2v;
typedef __attribute__((ext_vector_type(4))) unsigned short ushort4v;

static __device__ __forceinline__ unsigned short f2bf(float f) {
  union { float f; unsigned u; } v; v.f = f;
  unsigned r = v.u + 0x7fffu + ((v.u >> 16) & 1u);
  return (unsigned short)(r >> 16);
}
static __device__ __forceinline__ float bf2f(unsigned short h) {
  union { unsigned u; float f; } v; v.u = ((unsigned)h) << 16;
  return v.f;
}

#define GLDS(gp, lp) __builtin_amdgcn_global_load_lds( \
    (const __attribute__((address_space(1))) unsigned int*)(const void*)(gp), \
    (__attribute__((address_space(3))) unsigned int*)(void*)(lp), 16, 0, 0)

// ---------------------------------------------------------------- LayerNorm (f32 out)
__global__ __launch_bounds__(256) void ln_f32_kernel(const float* __restrict__ x,
    const float* __restrict__ g, const float* __restrict__ b, float* __restrict__ y)
{
  int row = blockIdx.x;
  int t = threadIdx.x;
  const float* xr = x + (size_t)row * D_;
  float2 v = *(const float2*)(xr + t * 2);
  float s  = v.x + v.y;
  float s2 = v.x * v.x + v.y * v.y;
#pragma unroll
  for (int off = 32; off; off >>= 1) {
    s  += __shfl_down(s,  off, 64);
    s2 += __shfl_down(s2, off, 64);
  }
  __shared__ float rs[4], rq[4];
  if ((t & 63) == 0) { rs[t >> 6] = s; rq[t >> 6] = s2; }
  __syncthreads();
  float S  = rs[0] + rs[1] + rs[2] + rs[3];
  float S2 = rq[0] + rq[1] + rq[2] + rq[3];
  float mean = S * (1.0f / D_);
  float var  = S2 * (1.0f / D_) - mean * mean;
  float r = 1.0f / sqrtf(var + 1e-5f);
  float2 gv = *(const float2*)(g + t * 2);
  float2 bv = *(const float2*)(b + t * 2);
  float2 o;
  o.x = (v.x - mean) * r * gv.x + bv.x;
  o.y = (v.y - mean) * r * gv.y + bv.y;
  *(float2*)(y + (size_t)row * D_ + t * 2) = o;
}

// ---------------------------------------------------------------- LayerNorm (bf16 out)
__global__ __launch_bounds__(256) void ln_bf16_kernel(const float* __restrict__ x,
    const float* __restrict__ g, const float* __restrict__ b, unsigned short* __restrict__ y)
{
  int row = blockIdx.x;
  int t = threadIdx.x;
  const float* xr = x + (size_t)row * D_;
  float2 v = *(const float2*)(xr + t * 2);
  float s  = v.x + v.y;
  float s2 = v.x * v.x + v.y * v.y;
#pragma unroll
  for (int off = 32; off; off >>= 1) {
    s  += __shfl_down(s,  off, 64);
    s2 += __shfl_down(s2, off, 64);
  }
  __shared__ float rs[4], rq[4];
  if ((t & 63) == 0) { rs[t >> 6] = s; rq[t >> 6] = s2; }
  __syncthreads();
  float S  = rs[0] + rs[1] + rs[2] + rs[3];
  float S2 = rq[0] + rq[1] + rq[2] + rq[3];
  float mean = S * (1.0f / D_);
  float var  = S2 * (1.0f / D_) - mean * mean;
  float r = 1.0f / sqrtf(var + 1e-5f);
  float2 gv = *(const float2*)(g + t * 2);
  float2 bv = *(const float2*)(b + t * 2);
  ushort2v o;
  o.x = f2bf((v.x - mean) * r * gv.x + bv.x);
  o.y = f2bf((v.y - mean) * r * gv.y + bv.y);
  *(ushort2v*)(y + (size_t)row * D_ + t * 2) = o;
}

// ---------------------------------------------------------------- weight fp32[K][N] -> bf16[N][K]
__global__ __launch_bounds__(256) void wtr_kernel(const float* __restrict__ W,
    unsigned short* __restrict__ Wt, int K, int N)
{
  __shared__ float tile[32][33];
  const float* Wl = W + (size_t)blockIdx.z * K * N;
  unsigned short* Wtl = Wt + (size_t)blockIdx.z * K * N;
  int n0 = blockIdx.x * 32, k0 = blockIdx.y * 32;
  int c = threadIdx.x & 31, r = threadIdx.x >> 5;  // r in 0..7
#pragma unroll
  for (int it = 0; it < 4; ++it) {
    int kk = r + it * 8;
    tile[kk][c] = Wl[(size_t)(k0 + kk) * N + n0 + c];
  }
  __syncthreads();
#pragma unroll
  for (int it = 0; it < 4; ++it) {
    int nn = r + it * 8;
    Wtl[(size_t)(n0 + nn) * K + k0 + c] = f2bf(tile[c][nn]);
  }
}

// ---------------------------------------------------------------- bf16 MFMA GEMM
// C[M,N] = epi(A[M,K]bf16 @ Wt[N,K]bf16^T + bias)
// EPI: 0 = none -> bf16 out, 1 = silu -> bf16 out, 2 = residual -> f32 out (C = R + alpha*val)
// 128x128 tile, BK=32, 256 thr (4 waves 2x2), 4x4 frag of 16x16x32 per wave.
template<int EPI>
__global__ __launch_bounds__(256) void gemm_mfma(
    const unsigned short* __restrict__ A, const unsigned short* __restrict__ Wt,
    const float* __restrict__ bias, const float* __restrict__ R, void* __restrict__ Cv,
    int N, int K, float alpha)
{
  __shared__ __align__(16) unsigned short As[128 * 32];
  __shared__ __align__(16) unsigned short Bs[128 * 32];
  int t = threadIdx.x;
  int row0 = blockIdx.y * 128, col0 = blockIdx.x * 128;
  int l = t & 63, w = t >> 6, wm = w >> 1, wn = w & 1;

  // staging: chunk c covers LDS bytes [c*16, c*16+16); row=c>>2, lds slot=c&3.
  // LDS slot qq at row r holds logical k-slot (qq ^ (r&3))  [XOR swizzle, source-side]
  int c0 = t, c1 = t + 256;
  int r0 = c0 >> 2, r1 = c1 >> 2;
  int s0 = (c0 & 3) ^ (r0 & 3), s1 = (c1 & 3) ^ (r1 & 3);
  const unsigned short* agp0 = A + (size_t)(row0 + r0) * K + s0 * 8;
  const unsigned short* agp1 = A + (size_t)(row0 + r1) * K + s1 * 8;
  const unsigned short* bgp0 = Wt + (size_t)(col0 + r0) * K + s0 * 8;
  const unsigned short* bgp1 = Wt + (size_t)(col0 + r1) * K + s1 * 8;
  unsigned short* lA0 = As + c0 * 8;
  unsigned short* lA1 = As + c1 * 8;
  unsigned short* lB0 = Bs + c0 * 8;
  unsigned short* lB1 = Bs + c1 * 8;

  // fragment read offsets (swizzled): row*32 + ((l>>4)^(l&3))*8
  int lrow = (l >> 4) * 4, lcol = l & 15;
  int slot = ((l >> 4) ^ (l & 3)) * 8;
  int aoff[4], boff[4];
#pragma unroll
  for (int i = 0; i < 4; ++i) {
    aoff[i] = (wm * 64 + i * 16 + lcol) * 32 + slot;
    boff[i] = (wn * 64 + i * 16 + lcol) * 32 + slot;
  }

  f32x4 acc[4][4] = {};
  for (int k0 = 0; k0 < K; k0 += 32) {
    GLDS(agp0, lA0); GLDS(agp1, lA1);
    GLDS(bgp0, lB0); GLDS(bgp1, lB1);
    agp0 += 32; agp1 += 32; bgp0 += 32; bgp1 += 32;
    __syncthreads();
    short8 af[4], bfr[4];
#pragma unroll
    for (int i = 0; i < 4; ++i) af[i]  = *(const short8*)(As + aoff[i]);
#pragma unroll
    for (int j = 0; j < 4; ++j) bfr[j] = *(const short8*)(Bs + boff[j]);
#pragma unroll
    for (int i = 0; i < 4; ++i)
#pragma unroll
      for (int j = 0; j < 4; ++j)
        acc[i][j] = __builtin_amdgcn_mfma_f32_16x16x32_bf16(af[i], bfr[j], acc[i][j], 0, 0, 0);
    __syncthreads();
  }

  float bj[4];
#pragma unroll
  for (int j = 0; j < 4; ++j) bj[j] = bias[col0 + wn * 64 + j * 16 + lcol];

#pragma unroll
  for (int i = 0; i < 4; ++i) {
    int gr0 = row0 + wm * 64 + i * 16 + lrow;
#pragma unroll
    for (int j = 0; j < 4; ++j) {
      int gc = col0 + wn * 64 + j * 16 + lcol;
#pragma unroll
      for (int q = 0; q < 4; ++q) {
        float v = acc[i][j][q] + bj[j];
        size_t off = (size_t)(gr0 + q) * N + gc;
        if constexpr (EPI == 0) {
          ((unsigned short*)Cv)[off] = f2bf(v);
        } else if constexpr (EPI == 1) {
          v = v / (1.0f + expf(-v));
          ((unsigned short*)Cv)[off] = f2bf(v);
        } else {
          ((float*)Cv)[off] = R[off] + alpha * v;
        }
      }
    }
  }
}

// ---------------------------------------------------------------- windowed attention (bf16 in/out)
__global__ __launch_bounds__(256) void attn_kernel(const unsigned short* __restrict__ QKV,
                                                   unsigned short* __restrict__ O)
{
  __shared__ float Qs[64][68];
  __shared__ float Ks[128][68];
  __shared__ float Vs[128][68];
  __shared__ float S[64][132];
  int qt = blockIdx.x, h = blockIdx.y, b = blockIdx.z;
  int t = threadIdx.x;
  int q0 = qt * 64;
  int jbase = q0 - 32;

  for (int i = t; i < 64 * 8; i += 256) {        // Q: 4096 elems, 8/thread-chunk
    int r = i >> 3, c8 = (i & 7) << 3;
    short8 raw = *(const short8*)(QKV + ((size_t)(b * T_ + q0 + r)) * 1536 + h * DH_ + c8);
#pragma unroll
    for (int j = 0; j < 8; ++j) Qs[r][c8 + j] = bf2f((unsigned short)raw[j]);
  }
  for (int i = t; i < 128 * 8; i += 256) {       // K and V
    int r = i >> 3, c8 = (i & 7) << 3;
    int jg = jbase + r;
    if ((unsigned)jg < (unsigned)T_) {
      const unsigned short* kp = QKV + ((size_t)(b * T_ + jg)) * 1536 + 512 + h * DH_ + c8;
      short8 kr = *(const short8*)kp;
      short8 vr = *(const short8*)(kp + 512);
#pragma unroll
      for (int j = 0; j < 8; ++j) {
        Ks[r][c8 + j] = bf2f((unsigned short)kr[j]);
        Vs[r][c8 + j] = bf2f((unsigned short)vr[j]);
      }
    } else {
#pragma unroll
      for (int j = 0; j < 8; ++j) { Ks[r][c8 + j] = 0.f; Vs[r][c8 + j] = 0.f; }
    }
  }
  __syncthreads();

  int q = t >> 2, l4 = t & 3;
  int qg = q0 + q;
  const float scale = 0.125f;
  for (int jj = 0; jj < 32; ++jj) {
    int j = (jj << 2) | l4;
    float acc = 0.f;
#pragma unroll
    for (int d = 0; d < 64; d += 4) {
      float4 qv = *(const float4*)&Qs[q][d];
      float4 kv = *(const float4*)&Ks[j][d];
      acc += qv.x * kv.x + qv.y * kv.y + qv.z * kv.z + qv.w * kv.w;
    }
    int jg = jbase + j;
    int dd = jg - qg;
    bool ok = ((unsigned)jg < (unsigned)T_) && (dd <= 32) && (dd >= -32);
    S[q][j] = ok ? acc * scale : -__builtin_inff();
  }
  __syncthreads();

  float mx = -__builtin_inff();
  for (int jj = 0; jj < 32; ++jj) mx = fmaxf(mx, S[q][(jj << 2) | l4]);
  mx = fmaxf(mx, __shfl_xor(mx, 1, 64));
  mx = fmaxf(mx, __shfl_xor(mx, 2, 64));
  float sum = 0.f;
  for (int jj = 0; jj < 32; ++jj) {
    int j = (jj << 2) | l4;
    float e = expf(S[q][j] - mx);
    S[q][j] = e;
    sum += e;
  }
  sum += __shfl_xor(sum, 1, 64);
  sum += __shfl_xor(sum, 2, 64);
  float inv = 1.0f / sum;
  __syncthreads();

  int d0 = l4 << 4;
  float acc[16] = {};
  for (int j = 0; j < 128; ++j) {
    float p = S[q][j];
#pragma unroll
    for (int c = 0; c < 16; c += 4) {
      float4 v4 = *(const float4*)&Vs[j][d0 + c];
      acc[c + 0] = fmaf(p, v4.x, acc[c + 0]);
      acc[c + 1] = fmaf(p, v4.y, acc[c + 1]);
      acc[c + 2] = fmaf(p, v4.z, acc[c + 2]);
      acc[c + 3] = fmaf(p, v4.w, acc[c + 3]);
    }
  }
  unsigned short* op = O + ((size_t)(b * T_ + qg)) * D_ + h * DH_ + d0;
#pragma unroll
  for (int c = 0; c < 16; c += 4) {
    ushort4v o4;
    o4.x = f2bf(acc[c + 0] * inv); o4.y = f2bf(acc[c + 1] * inv);
    o4.z = f2bf(acc[c + 2] * inv); o4.w = f2bf(acc[c + 3] * inv);
    *(ushort4v*)(op + c) = o4;
  }
}

// ---------------------------------------------------------------- GLU (bf16 in, bf16 out)
__global__ __launch_bounds__(256) void glu_kernel(const unsigned short* __restrict__ P,
                                                  unsigned short* __restrict__ G)
{
  int idx = blockIdx.x * 256 + threadIdx.x;    // 4-elem chunk over [ROWS][EC]
  int row = idx >> 8;
  int c4  = (idx & 255) << 2;
  const unsigned short* p = P + (size_t)row * (2 * EC_);
  ushort4v a = *(const ushort4v*)(p + c4);
  ushort4v g = *(const ushort4v*)(p + EC_ + c4);
  ushort4v o;
#pragma unroll
  for (int j = 0; j < 4; ++j) {
    float av = bf2f(a[j]), gv = bf2f(g[j]);
    o[j] = f2bf(av * (1.0f / (1.0f + expf(-gv))));
  }
  *(ushort4v*)(G + (size_t)row * EC_ + c4) = o;
}

// ---------------------------------------------------------------- depthwise conv k=31 (bf16 in, f32 out)
#define TT_ 16
__global__ __launch_bounds__(256) void dwconv_kernel(const unsigned short* __restrict__ X,
    const float* __restrict__ w, const float* __restrict__ bias, float* __restrict__ Y)
{
  int t = threadIdx.x;
  int gid = blockIdx.x;           // B * (T/TT_) * (EC/256) = 2048
  int ecb = gid & 3;
  int tt  = (gid >> 2) & 63;
  int b   = gid >> 8;
  int e  = ecb * 256 + t;
  int t0 = tt * TT_;
  const unsigned short* xp = X + (size_t)b * T_ * EC_ + e;

  float wr[KW_];
#pragma unroll
  for (int k = 0; k < KW_; ++k) wr[k] = w[e * KW_ + k];
  float out[TT_];
  float bv = bias[e];
#pragma unroll
  for (int i = 0; i < TT_; ++i) out[i] = bv;

#pragma unroll
  for (int j = 0; j < TT_ + KW_ - 1; ++j) {
    int tj = t0 - 15 + j;
    float xv = ((unsigned)tj < (unsigned)T_) ? bf2f(xp[(size_t)tj * EC_]) : 0.f;
#pragma unroll
    for (int i = 0; i < TT_; ++i) {
      int k = j - i;
      if (k >= 0 && k < KW_) out[i] = fmaf(xv, wr[k], out[i]);
    }
  }
  float* yp = Y + ((size_t)b * T_ + t0) * EC_ + e;
#pragma unroll
  for (int i = 0; i < TT_; ++i) yp[(size_t)i * EC_] = out[i];
}

// ---------------------------------------------------------------- GroupNorm
__global__ __launch_bounds__(256) void gn_reduce_kernel(const float* __restrict__ X,
                                                        float* __restrict__ partial)
{
  int b = blockIdx.y, blk = blockIdx.x;
  const float* p = X + (size_t)b * (T_ * EC_) + (size_t)blk * 8192;
  int t = threadIdx.x;
  float s = 0.f, s2 = 0.f;
#pragma unroll
  for (int i = 0; i < 8; ++i) {
    float4 v = *(const float4*)(p + (size_t)((i << 8) + t) * 4);
    s  += v.x + v.y + v.z + v.w;
    s2 += v.x * v.x + v.y * v.y + v.z * v.z + v.w * v.w;
  }
#pragma unroll
  for (int off = 32; off; off >>= 1) {
    s  += __shfl_down(s,  off, 64);
    s2 += __shfl_down(s2, off, 64);
  }
  __shared__ float rs[4], rq[4];
  if ((t & 63) == 0) { rs[t >> 6] = s; rq[t >> 6] = s2; }
  __syncthreads();
  if (t == 0) {
    partial[(b * 128 + blk) * 2]     = rs[0] + rs[1] + rs[2] + rs[3];
    partial[(b * 128 + blk) * 2 + 1] = rq[0] + rq[1] + rq[2] + rq[3];
  }
}

__global__ __launch_bounds__(128) void gn_stats_kernel(const float* __restrict__ partial,
                                                       float* __restrict__ stats)
{
  int b = blockIdx.x, t = threadIdx.x;
  float s  = partial[(b * 128 + t) * 2];
  float s2 = partial[(b * 128 + t) * 2 + 1];
#pragma unroll
  for (int off = 32; off; off >>= 1) {
    s  += __shfl_down(s,  off, 64);
    s2 += __shfl_down(s2, off, 64);
  }
  __shared__ float rs[2], rq[2];
  if ((t & 63) == 0) { rs[t >> 6] = s; rq[t >> 6] = s2; }
  __syncthreads();
  if (t == 0) {
    float S = rs[0] + rs[1], S2 = rq[0] + rq[1];
    const float n = (float)(T_ * EC_);
    float mean = S / n;
    float var  = S2 / n - mean * mean;
    stats[b * 2]     = mean;
    stats[b * 2 + 1] = 1.0f / sqrtf(var + 1e-5f);
  }
}

// reads f32 conv-out, writes silu(gn(..)) as bf16
__global__ __launch_bounds__(256) void gn_apply_kernel(const float* __restrict__ X,
    const float* __restrict__ stats, const float* __restrict__ g, const float* __restrict__ bb,
    unsigned short* __restrict__ out)
{
  int idx = blockIdx.x * 256 + threadIdx.x;   // 4-elem chunks over [B,T,EC]
  int e4 = (idx & 255) << 2;
  int bt = idx >> 8;
  int b  = bt >> 10;
  float mean = stats[b * 2], rstd = stats[b * 2 + 1];
  float4 v  = *(const float4*)(X + (size_t)idx * 4);
  float4 gv = *(const float4*)(g + e4);
  float4 bv = *(const float4*)(bb + e4);
  float vv[4] = {v.x, v.y, v.z, v.w};
  float gg[4] = {gv.x, gv.y, gv.z, gv.w};
  float bbv[4] = {bv.x, bv.y, bv.z, bv.w};
  ushort4v o;
#pragma unroll
  for (int j = 0; j < 4; ++j) {
    float u = (vv[j] - mean) * rstd * gg[j] + bbv[j];
    o[j] = f2bf(u * (1.0f / (1.0f + expf(-u))));
  }
  *(ushort4v*)(out + (size_t)idx * 4) = o;
}

// ---------------------------------------------------------------- launch
extern "C" void kernel_launch(void* const* d_in, const int* in_sizes, int n_in,
                              void* d_out, int out_size, void* d_ws, size_t ws_size,
                              hipStream_t stream)
{
  const float* in_x      = (const float*)d_in[0];
  const float* ffn1_ln_g = (const float*)d_in[1];
  const float* ffn1_ln_b = (const float*)d_in[2];
  const float* ffn1_w1   = (const float*)d_in[3];
  const float* ffn1_b1   = (const float*)d_in[4];
  const float* ffn1_w2   = (const float*)d_in[5];
  const float* ffn1_b2   = (const float*)d_in[6];
  const float* attn_ln_g = (const float*)d_in[7];
  const float* attn_ln_b = (const float*)d_in[8];
  const float* qkv_w     = (const float*)d_in[9];
  const float* qkv_b     = (const float*)d_in[10];
  const float* outp_w    = (const float*)d_in[11];
  const float* outp_b    = (const float*)d_in[12];
  const float* conv_ln_g = (const float*)d_in[13];
  const float* conv_ln_b = (const float*)d_in[14];
  const float* pw1_w     = (const float*)d_in[15];
  const float* pw1_b     = (const float*)d_in[16];
  const float* dw_w      = (const float*)d_in[17];
  const float* dw_b      = (const float*)d_in[18];
  const float* gn_g      = (const float*)d_in[19];
  const float* gn_b      = (const float*)d_in[20];
  const float* pw2_w     = (const float*)d_in[21];
  const float* pw2_b     = (const float*)d_in[22];
  const float* ffn2_ln_g = (const float*)d_in[23];
  const float* ffn2_ln_b = (const float*)d_in[24];
  const float* ffn2_w1   = (const float*)d_in[25];
  const float* ffn2_b1   = (const float*)d_in[26];
  const float* ffn2_w2   = (const float*)d_in[27];
  const float* ffn2_b2   = (const float*)d_in[28];
  const float* blk_ln_g  = (const float*)d_in[29];
  const float* blk_ln_b  = (const float*)d_in[30];
  const float* fin_ln_g  = (const float*)d_in[31];
  const float* fin_ln_b  = (const float*)d_in[32];

  char* p = (char*)d_ws;
  float* x    = (float*)p;          p += (size_t)ROWS * D_ * 4;        // f32 residual stream
  float* big3 = (float*)p;          p += (size_t)ROWS * EC_ * 4;       // conv out f32
  float* red  = (float*)p;          p += 4096 * 4;
  unsigned short* abuf  = (unsigned short*)p; p += (size_t)ROWS * D_ * 2;   // ln/attn out bf16
  unsigned short* inner = (unsigned short*)p; p += (size_t)ROWS * FF_ * 2;  // w1/qkv/pw1 out bf16
  unsigned short* big2  = (unsigned short*)p; p += (size_t)ROWS * EC_ * 2;  // GLU out / GN out bf16
  unsigned short* wt_w1a = (unsigned short*)p; p += (size_t)L_ * D_ * FF_ * 2;
  unsigned short* wt_w1b = (unsigned short*)p; p += (size_t)L_ * FF_ * D_ * 2;
  unsigned short* wt_qkv = (unsigned short*)p; p += (size_t)L_ * D_ * 1536 * 2;
  unsigned short* wt_out = (unsigned short*)p; p += (size_t)L_ * D_ * D_ * 2;
  unsigned short* wt_pw1 = (unsigned short*)p; p += (size_t)L_ * D_ * 2048 * 2;
  unsigned short* wt_pw2 = (unsigned short*)p; p += (size_t)L_ * EC_ * D_ * 2;
  unsigned short* wt_w2a = (unsigned short*)p; p += (size_t)L_ * D_ * FF_ * 2;
  unsigned short* wt_w2b = (unsigned short*)p; p += (size_t)L_ * FF_ * D_ * 2;

  hipMemcpyAsync(x, in_x, sizeof(float) * (size_t)ROWS * D_,
                 hipMemcpyDeviceToDevice, stream);

  dim3 blk256(256);
  // weight convert+transpose (all layers, once per call)
  wtr_kernel<<<dim3(FF_/32,  D_/32,  L_), blk256, 0, stream>>>(ffn1_w1, wt_w1a, D_, FF_);
  wtr_kernel<<<dim3(D_/32,   FF_/32, L_), blk256, 0, stream>>>(ffn1_w2, wt_w1b, FF_, D_);
  wtr_kernel<<<dim3(1536/32, D_/32,  L_), blk256, 0, stream>>>(qkv_w,   wt_qkv, D_, 1536);
  wtr_kernel<<<dim3(D_/32,   D_/32,  L_), blk256, 0, stream>>>(outp_w,  wt_out, D_, D_);
  wtr_kernel<<<dim3(2048/32, D_/32,  L_), blk256, 0, stream>>>(pw1_w,   wt_pw1, D_, 2048);
  wtr_kernel<<<dim3(D_/32,   EC_/32, L_), blk256, 0, stream>>>(pw2_w,   wt_pw2, EC_, D_);
  wtr_kernel<<<dim3(FF_/32,  D_/32,  L_), blk256, 0, stream>>>(ffn2_w1, wt_w2a, D_, FF_);
  wtr_kernel<<<dim3(D_/32,   FF_/32, L_), blk256, 0, stream>>>(ffn2_w2, wt_w2b, FF_, D_);

  for (int l = 0; l < L_; ++l) {
    // ---- FFN1 ----
    ln_bf16_kernel<<<ROWS, blk256, 0, stream>>>(x, ffn1_ln_g + l*D_, ffn1_ln_b + l*D_, abuf);
    gemm_mfma<1><<<dim3(FF_/128, ROWS/128), blk256, 0, stream>>>(
        abuf, wt_w1a + (size_t)l*D_*FF_, ffn1_b1 + l*FF_, nullptr, inner, FF_, D_, 0.f);
    gemm_mfma<2><<<dim3(D_/128, ROWS/128), blk256, 0, stream>>>(
        inner, wt_w1b + (size_t)l*FF_*D_, ffn1_b2 + l*D_, x, x, D_, FF_, 0.5f);

    // ---- local windowed MHSA ----
    ln_bf16_kernel<<<ROWS, blk256, 0, stream>>>(x, attn_ln_g + l*D_, attn_ln_b + l*D_, abuf);
    gemm_mfma<0><<<dim3(1536/128, ROWS/128), blk256, 0, stream>>>(
        abuf, wt_qkv + (size_t)l*D_*1536, qkv_b + l*1536, nullptr, inner, 1536, D_, 0.f);
    attn_kernel<<<dim3(T_/64, H_, B_), blk256, 0, stream>>>(inner, abuf);
    gemm_mfma<2><<<dim3(D_/128, ROWS/128), blk256, 0, stream>>>(
        abuf, wt_out + (size_t)l*D_*D_, outp_b + l*D_, x, x, D_, D_, 1.0f);

    // ---- conv module ----
    ln_bf16_kernel<<<ROWS, blk256, 0, stream>>>(x, conv_ln_g + l*D_, conv_ln_b + l*D_, abuf);
    gemm_mfma<0><<<dim3(2048/128, ROWS/128), blk256, 0, stream>>>(
        abuf, wt_pw1 + (size_t)l*D_*2048, pw1_b + l*2048, nullptr, inner, 2048, D_, 0.f);
    glu_kernel<<<(ROWS * EC_ / 4) / 256, blk256, 0, stream>>>(inner, big2);
    dwconv_kernel<<<B_ * (T_/TT_) * (EC_/256), blk256, 0, stream>>>(
        big2, dw_w + (size_t)l*EC_*KW_, dw_b + l*EC_, big3);
    gn_reduce_kernel<<<dim3(128, B_), blk256, 0, stream>>>(big3, red);
    gn_stats_kernel<<<B_, 128, 0, stream>>>(red, red + 2048);
    gn_apply_kernel<<<(ROWS * EC_ / 4) / 256, blk256, 0, stream>>>(
        big3, red + 2048, gn_g + l*EC_, gn_b + l*EC_, big2);
    gemm_mfma<2><<<dim3(D_/128, ROWS/128), blk256, 0, stream>>>(
        big2, wt_pw2 + (size_t)l*EC_*D_, pw2_b + l*D_, x, x, D_, EC_, 1.0f);

    // ---- FFN2 ----
    ln_bf16_kernel<<<ROWS, blk256, 0, stream>>>(x, ffn2_ln_g + l*D_, ffn2_ln_b + l*D_, abuf);
    gemm_mfma<1><<<dim3(FF_/128, ROWS/128), blk256, 0, stream>>>(
        abuf, wt_w2a + (size_t)l*D_*FF_, ffn2_b1 + l*FF_, nullptr, inner, FF_, D_, 0.f);
    gemm_mfma<2><<<dim3(D_/128, ROWS/128), blk256, 0, stream>>>(
        inner, wt_w2b + (size_t)l*FF_*D_, ffn2_b2 + l*D_, x, x, D_, FF_, 0.5f);

    // ---- per-block final LN (in place, f32) ----
    ln_f32_kernel<<<ROWS, blk256, 0, stream>>>(x, blk_ln_g + l*D_, blk_ln_b + l*D_, x);
  }

  ln_f32_kernel<<<ROWS, blk256, 0, stream>>>(x, fin_ln_g, fin_ln_b, (float*)d_out);
}

// Round 4
// 1466.197 us; speedup vs baseline: 5.4713x; 1.3524x over previous
//
#include <hip/hip_runtime.h>
#include <math.h>

#define L_ 4
#define D_ 512
#define H_ 8
#define T_ 1024
#define B_ 8
#define FF_ 2048
#define EC_ 1024
#define KW_ 31
#define DH_ 64
#define ROWS (B_*T_)   // 8192

typedef __attribute__((ext_vector_type(8))) short short8;
typedef __attribute__((ext_vector_type(4))) float f32x4;
typedef __attribute__((ext_vector_type(2))) unsigned short ushort2v;
typedef __attribute__((ext_vector_type(4))) unsigned short ushort4v;

static __device__ __forceinline__ unsigned short f2bf(float f) {
  union { float f; unsigned u; } v; v.f = f;
  unsigned r = v.u + 0x7fffu + ((v.u >> 16) & 1u);
  return (unsigned short)(r >> 16);
}
static __device__ __forceinline__ float bf2f(unsigned short h) {
  union { unsigned u; float f; } v; v.u = ((unsigned)h) << 16;
  return v.f;
}

#define GLDS(gp, lp) __builtin_amdgcn_global_load_lds( \
    (const __attribute__((address_space(1))) unsigned int*)(const void*)(gp), \
    (__attribute__((address_space(3))) unsigned int*)(void*)(lp), 16, 0, 0)

// 8-slot-per-row XOR swizzle (rows of 8x16B): slot' = slot ^ f(row), f covers 0..7
#define SW8(row, slot) ((slot) ^ (((row) ^ ((row) >> 3)) & 7))

// ---------------------------------------------------------------- LayerNorm (bf16 out)
__global__ __launch_bounds__(256) void ln_bf16_kernel(const float* __restrict__ x,
    const float* __restrict__ g, const float* __restrict__ b, unsigned short* __restrict__ y)
{
  int row = blockIdx.x;
  int t = threadIdx.x;
  const float* xr = x + (size_t)row * D_;
  float2 v = *(const float2*)(xr + t * 2);
  float s  = v.x + v.y;
  float s2 = v.x * v.x + v.y * v.y;
#pragma unroll
  for (int off = 32; off; off >>= 1) {
    s  += __shfl_down(s,  off, 64);
    s2 += __shfl_down(s2, off, 64);
  }
  __shared__ float rs[4], rq[4];
  if ((t & 63) == 0) { rs[t >> 6] = s; rq[t >> 6] = s2; }
  __syncthreads();
  float S  = rs[0] + rs[1] + rs[2] + rs[3];
  float S2 = rq[0] + rq[1] + rq[2] + rq[3];
  float mean = S * (1.0f / D_);
  float var  = S2 * (1.0f / D_) - mean * mean;
  float r = 1.0f / sqrtf(var + 1e-5f);
  float2 gv = *(const float2*)(g + t * 2);
  float2 bv = *(const float2*)(b + t * 2);
  ushort2v o;
  o.x = f2bf((v.x - mean) * r * gv.x + bv.x);
  o.y = f2bf((v.y - mean) * r * gv.y + bv.y);
  *(ushort2v*)(y + (size_t)row * D_ + t * 2) = o;
}

// ---------------------------------------------------------------- dual LayerNorm
// y1 = LN(x; g1,b1) [f32]; y2 = LN(y1; g2,b2) [bf16 if BF2 else f32]
template<bool BF2>
__global__ __launch_bounds__(256) void ln_dual_kernel(const float* __restrict__ x,
    const float* __restrict__ g1, const float* __restrict__ b1,
    const float* __restrict__ g2, const float* __restrict__ b2,
    float* __restrict__ y1, void* __restrict__ y2)
{
  int row = blockIdx.x;
  int t = threadIdx.x;
  __shared__ float rs1[4], rq1[4], rs2[4], rq2[4];
  float2 v = *(const float2*)(x + (size_t)row * D_ + t * 2);
  float s  = v.x + v.y;
  float s2 = v.x * v.x + v.y * v.y;
#pragma unroll
  for (int off = 32; off; off >>= 1) {
    s  += __shfl_down(s,  off, 64);
    s2 += __shfl_down(s2, off, 64);
  }
  if ((t & 63) == 0) { rs1[t >> 6] = s; rq1[t >> 6] = s2; }
  __syncthreads();
  float S  = rs1[0] + rs1[1] + rs1[2] + rs1[3];
  float S2 = rq1[0] + rq1[1] + rq1[2] + rq1[3];
  float mean = S * (1.0f / D_);
  float var  = S2 * (1.0f / D_) - mean * mean;
  float r = 1.0f / sqrtf(var + 1e-5f);
  float2 g1v = *(const float2*)(g1 + t * 2);
  float2 b1v = *(const float2*)(b1 + t * 2);
  float2 y;
  y.x = (v.x - mean) * r * g1v.x + b1v.x;
  y.y = (v.y - mean) * r * g1v.y + b1v.y;
  *(float2*)(y1 + (size_t)row * D_ + t * 2) = y;
  // second LN over y
  float u  = y.x + y.y;
  float u2 = y.x * y.x + y.y * y.y;
#pragma unroll
  for (int off = 32; off; off >>= 1) {
    u  += __shfl_down(u,  off, 64);
    u2 += __shfl_down(u2, off, 64);
  }
  if ((t & 63) == 0) { rs2[t >> 6] = u; rq2[t >> 6] = u2; }
  __syncthreads();
  float U  = rs2[0] + rs2[1] + rs2[2] + rs2[3];
  float U2 = rq2[0] + rq2[1] + rq2[2] + rq2[3];
  float mean2 = U * (1.0f / D_);
  float var2  = U2 * (1.0f / D_) - mean2 * mean2;
  float r2 = 1.0f / sqrtf(var2 + 1e-5f);
  float2 g2v = *(const float2*)(g2 + t * 2);
  float2 b2v = *(const float2*)(b2 + t * 2);
  float zx = (y.x - mean2) * r2 * g2v.x + b2v.x;
  float zy = (y.y - mean2) * r2 * g2v.y + b2v.y;
  if constexpr (BF2) {
    ushort2v o; o.x = f2bf(zx); o.y = f2bf(zy);
    *(ushort2v*)((unsigned short*)y2 + (size_t)row * D_ + t * 2) = o;
  } else {
    float2 o; o.x = zx; o.y = zy;
    *(float2*)((float*)y2 + (size_t)row * D_ + t * 2) = o;
  }
}

// ---------------------------------------------------------------- weight fp32[K][N] -> bf16[N][K]
__global__ __launch_bounds__(256) void wtr_kernel(const float* __restrict__ W,
    unsigned short* __restrict__ Wt, int K, int N)
{
  __shared__ float tile[32][33];
  const float* Wl = W + (size_t)blockIdx.z * K * N;
  unsigned short* Wtl = Wt + (size_t)blockIdx.z * K * N;
  int n0 = blockIdx.x * 32, k0 = blockIdx.y * 32;
  int c = threadIdx.x & 31, r = threadIdx.x >> 5;
#pragma unroll
  for (int it = 0; it < 4; ++it) {
    int kk = r + it * 8;
    tile[kk][c] = Wl[(size_t)(k0 + kk) * N + n0 + c];
  }
  __syncthreads();
#pragma unroll
  for (int it = 0; it < 4; ++it) {
    int nn = r + it * 8;
    Wtl[(size_t)(n0 + nn) * K + k0 + c] = f2bf(tile[c][nn]);
  }
}

// ---------------------------------------------------------------- bf16 MFMA GEMM (2-phase dbuf)
// C[M,N] = epi(A[M,K]bf16 @ Wt[N,K]bf16^T + bias)
// EPI: 0=none->bf16, 1=silu->bf16, 2=residual->f32 (C = R + alpha*val)
template<int EPI>
__global__ __launch_bounds__(256) void gemm_mfma(
    const unsigned short* __restrict__ A, const unsigned short* __restrict__ Wt,
    const float* __restrict__ bias, const float* __restrict__ R, void* __restrict__ Cv,
    int N, int K, float alpha)
{
  __shared__ __align__(16) unsigned short As[2][128 * 32];
  __shared__ __align__(16) unsigned short Bs[2][128 * 32];
  int t = threadIdx.x;
  int row0 = blockIdx.y * 128, col0 = blockIdx.x * 128;
  int l = t & 63, w = t >> 6, wm = w >> 1, wn = w & 1;

  // staging: chunk c -> LDS bytes [c*16,c*16+16): row=c>>2, lds slot=c&3 (linear).
  // source k-slot pre-swizzled: s = (c&3) ^ ((row>>1)&3)
  int c0 = t, c1 = t + 256;
  int r0 = c0 >> 2, r1 = c1 >> 2;
  int s0 = (c0 & 3) ^ ((r0 >> 1) & 3), s1 = (c1 & 3) ^ ((r1 >> 1) & 3);
  const unsigned short* agp0 = A + (size_t)(row0 + r0) * K + s0 * 8;
  const unsigned short* agp1 = A + (size_t)(row0 + r1) * K + s1 * 8;
  const unsigned short* bgp0 = Wt + (size_t)(col0 + r0) * K + s0 * 8;
  const unsigned short* bgp1 = Wt + (size_t)(col0 + r1) * K + s1 * 8;

  // fragment read offsets: row*32 + (kq ^ ((row>>1)&3))*8,  kq = l>>4
  int lrow = (l >> 4) * 4, lcol = l & 15;
  int slot = ((l >> 4) ^ ((lcol >> 1) & 3)) * 8;
  int aoff[4], boff[4];
#pragma unroll
  for (int i = 0; i < 4; ++i) {
    aoff[i] = (wm * 64 + i * 16 + lcol) * 32 + slot;
    boff[i] = (wn * 64 + i * 16 + lcol) * 32 + slot;
  }

  f32x4 acc[4][4] = {};
  int nt = K >> 5;
  // prologue: stage tile 0 into buf 0
  GLDS(agp0, As[0] + c0 * 8); GLDS(agp1, As[0] + c1 * 8);
  GLDS(bgp0, Bs[0] + c0 * 8); GLDS(bgp1, Bs[0] + c1 * 8);
  agp0 += 32; agp1 += 32; bgp0 += 32; bgp1 += 32;

  for (int kt = 0; kt < nt; ++kt) {
    __syncthreads();               // buf[kt&1] ready (vmcnt drained)
    int cur = kt & 1;
    if (kt + 1 < nt) {             // stage next tile while computing this one
      GLDS(agp0, As[cur ^ 1] + c0 * 8); GLDS(agp1, As[cur ^ 1] + c1 * 8);
      GLDS(bgp0, Bs[cur ^ 1] + c0 * 8); GLDS(bgp1, Bs[cur ^ 1] + c1 * 8);
      agp0 += 32; agp1 += 32; bgp0 += 32; bgp1 += 32;
    }
    const unsigned short* Ab = As[cur];
    const unsigned short* Bb = Bs[cur];
    short8 af[4], bfr[4];
#pragma unroll
    for (int i = 0; i < 4; ++i) af[i]  = *(const short8*)(Ab + aoff[i]);
#pragma unroll
    for (int j = 0; j < 4; ++j) bfr[j] = *(const short8*)(Bb + boff[j]);
#pragma unroll
    for (int i = 0; i < 4; ++i)
#pragma unroll
      for (int j = 0; j < 4; ++j)
        acc[i][j] = __builtin_amdgcn_mfma_f32_16x16x32_bf16(af[i], bfr[j], acc[i][j], 0, 0, 0);
  }

  float bj[4];
#pragma unroll
  for (int j = 0; j < 4; ++j) bj[j] = bias[col0 + wn * 64 + j * 16 + lcol];

#pragma unroll
  for (int i = 0; i < 4; ++i) {
    int gr0 = row0 + wm * 64 + i * 16 + lrow;
#pragma unroll
    for (int j = 0; j < 4; ++j) {
      int gc = col0 + wn * 64 + j * 16 + lcol;
#pragma unroll
      for (int q = 0; q < 4; ++q) {
        float v = acc[i][j][q] + bj[j];
        size_t off = (size_t)(gr0 + q) * N + gc;
        if constexpr (EPI == 0) {
          ((unsigned short*)Cv)[off] = f2bf(v);
        } else if constexpr (EPI == 1) {
          v = v / (1.0f + __expf(-v));
          ((unsigned short*)Cv)[off] = f2bf(v);
        } else {
          ((float*)Cv)[off] = R[off] + alpha * v;
        }
      }
    }
  }
}

// ---------------------------------------------------------------- MFMA windowed attention
// grid (T/64, H, B), 256 thr (4 waves). Wave w owns queries q0+w*16..+15.
__global__ __launch_bounds__(256) void attn_kernel(const unsigned short* __restrict__ QKV,
                                                   unsigned short* __restrict__ O)
{
  __shared__ __align__(16) unsigned short Ks[128 * 64];   // [j][d] swizzled
  __shared__ __align__(16) unsigned short Vt[64 * 128];   // [d][j] swizzled
  __shared__ __align__(16) unsigned short Ps[64 * 128];   // [q][j] swizzled
  int qt = blockIdx.x, h = blockIdx.y, b = blockIdx.z;
  int t = threadIdx.x;
  int l = t & 63, w = t >> 6;
  int q0 = qt * 64;
  int jbase = q0 - 32;

  // ---- stage K [128 rows][64 d] and V transposed [64 d][128 j], bf16 ----
#pragma unroll
  for (int i = 0; i < 4; ++i) {
    int c = t + i * 256;            // 0..1023
    int row = c >> 3, sl = c & 7;   // K row, 16B slot
    int jg = jbase + row;
    short8 kv = {};
    if ((unsigned)jg < (unsigned)T_)
      kv = *(const short8*)(QKV + ((size_t)(b * T_ + jg)) * 1536 + 512 + h * DH_ + sl * 8);
    *(short8*)(Ks + row * 64 + SW8(row, sl) * 8) = kv;
  }
#pragma unroll
  for (int i = 0; i < 4; ++i) {
    int c = t + i * 256;
    int row = c >> 3, d0 = (c & 7) * 8;   // V row j, d-range
    int jg = jbase + row;
    short8 vv = {};
    if ((unsigned)jg < (unsigned)T_)
      vv = *(const short8*)(QKV + ((size_t)(b * T_ + jg)) * 1536 + 1024 + h * DH_ + d0);
#pragma unroll
    for (int q = 0; q < 8; ++q) {
      int d = d0 + q;
      Vt[d * 128 + SW8(d, row >> 3) * 8 + (row & 7)] = (unsigned short)vv[q];
    }
  }
  // Q fragments straight from global: A-frag row = l&15, k = (l>>4)*8 + ks*32
  short8 qf[2];
#pragma unroll
  for (int ks = 0; ks < 2; ++ks)
    qf[ks] = *(const short8*)(QKV + ((size_t)(b * T_ + q0 + w * 16 + (l & 15))) * 1536
                              + h * DH_ + ks * 32 + (l >> 4) * 8);
  __syncthreads();

  // ---- QK^T: S[16q x 128j] per wave ----
  f32x4 sacc[8] = {};
#pragma unroll
  for (int jt = 0; jt < 8; ++jt) {
#pragma unroll
    for (int ks = 0; ks < 2; ++ks) {
      int row = jt * 16 + (l & 15);
      int sl = ks * 4 + (l >> 4);
      short8 kf = *(const short8*)(Ks + row * 64 + SW8(row, sl) * 8);
      sacc[jt] = __builtin_amdgcn_mfma_f32_16x16x32_bf16(qf[ks], kf, sacc[jt], 0, 0, 0);
    }
  }

  // ---- mask + scale + softmax (C layout: col j = l&15, row q = (l>>4)*4 + r) ----
  const float scale = 0.125f;
  int qgl0 = q0 + w * 16 + ((l >> 4) << 2);
  int jl = jbase + (l & 15);
  float m4[4] = {-3.0e38f, -3.0e38f, -3.0e38f, -3.0e38f};
#pragma unroll
  for (int jt = 0; jt < 8; ++jt) {
#pragma unroll
    for (int r = 0; r < 4; ++r) {
      float s = sacc[jt][r] * scale;
      int jg = jl + jt * 16;
      int dd = jg - (qgl0 + r);
      bool ok = ((unsigned)jg < (unsigned)T_) && (dd <= 32) && (dd >= -32);
      s = ok ? s : -3.0e38f;
      sacc[jt][r] = s;
      m4[r] = fmaxf(m4[r], s);
    }
  }
#pragma unroll
  for (int r = 0; r < 4; ++r) {
    m4[r] = fmaxf(m4[r], __shfl_xor(m4[r], 1, 64));
    m4[r] = fmaxf(m4[r], __shfl_xor(m4[r], 2, 64));
    m4[r] = fmaxf(m4[r], __shfl_xor(m4[r], 4, 64));
    m4[r] = fmaxf(m4[r], __shfl_xor(m4[r], 8, 64));
  }
  float sum4[4] = {0.f, 0.f, 0.f, 0.f};
#pragma unroll
  for (int jt = 0; jt < 8; ++jt) {
#pragma unroll
    for (int r = 0; r < 4; ++r) {
      float e = __expf(sacc[jt][r] - m4[r]);
      sum4[r] += e;
      int qrow = w * 16 + ((l >> 4) << 2) + r;
      int j = jt * 16 + (l & 15);
      Ps[qrow * 128 + SW8(qrow, j >> 3) * 8 + (j & 7)] = f2bf(e);
    }
  }
#pragma unroll
  for (int r = 0; r < 4; ++r) {
    sum4[r] += __shfl_xor(sum4[r], 1, 64);
    sum4[r] += __shfl_xor(sum4[r], 2, 64);
    sum4[r] += __shfl_xor(sum4[r], 4, 64);
    sum4[r] += __shfl_xor(sum4[r], 8, 64);
    sum4[r] = 1.0f / sum4[r];
  }

  // ---- PV: O[16q x 64d] per wave (P rows are wave-local; no barrier needed) ----
  f32x4 oacc[4] = {};
#pragma unroll
  for (int ks = 0; ks < 4; ++ks) {
    int prow = w * 16 + (l & 15);
    int sl = ks * 4 + (l >> 4);
    short8 pf = *(const short8*)(Ps + prow * 128 + SW8(prow, sl) * 8);
#pragma unroll
    for (int dt = 0; dt < 4; ++dt) {
      int vrow = dt * 16 + (l & 15);
      short8 vf = *(const short8*)(Vt + vrow * 128 + SW8(vrow, sl) * 8);
      oacc[dt] = __builtin_amdgcn_mfma_f32_16x16x32_bf16(pf, vf, oacc[dt], 0, 0, 0);
    }
  }
#pragma unroll
  for (int dt = 0; dt < 4; ++dt) {
#pragma unroll
    for (int r = 0; r < 4; ++r) {
      int qg = q0 + w * 16 + ((l >> 4) << 2) + r;
      int d = dt * 16 + (l & 15);
      O[((size_t)(b * T_ + qg)) * D_ + h * DH_ + d] = f2bf(oacc[dt][r] * sum4[r]);
    }
  }
}

// ---------------------------------------------------------------- GLU (bf16 in/out)
__global__ __launch_bounds__(256) void glu_kernel(const unsigned short* __restrict__ P,
                                                  unsigned short* __restrict__ G)
{
  int idx = blockIdx.x * 256 + threadIdx.x;
  int row = idx >> 8;
  int c4  = (idx & 255) << 2;
  const unsigned short* p = P + (size_t)row * (2 * EC_);
  ushort4v a = *(const ushort4v*)(p + c4);
  ushort4v g = *(const ushort4v*)(p + EC_ + c4);
  ushort4v o;
#pragma unroll
  for (int j = 0; j < 4; ++j) {
    float av = bf2f(a[j]), gv = bf2f(g[j]);
    o[j] = f2bf(av * (1.0f / (1.0f + __expf(-gv))));
  }
  *(ushort4v*)(G + (size_t)row * EC_ + c4) = o;
}

// ---------------------------------------------------------------- depthwise conv k=31 (bf16 in, f32 out)
#define TT_ 16
__global__ __launch_bounds__(256) void dwconv_kernel(const unsigned short* __restrict__ X,
    const float* __restrict__ w, const float* __restrict__ bias, float* __restrict__ Y)
{
  int t = threadIdx.x;
  int gid = blockIdx.x;
  int ecb = gid & 3;
  int tt  = (gid >> 2) & 63;
  int b   = gid >> 8;
  int e  = ecb * 256 + t;
  int t0 = tt * TT_;
  const unsigned short* xp = X + (size_t)b * T_ * EC_ + e;

  float wr[KW_];
#pragma unroll
  for (int k = 0; k < KW_; ++k) wr[k] = w[e * KW_ + k];
  float out[TT_];
  float bv = bias[e];
#pragma unroll
  for (int i = 0; i < TT_; ++i) out[i] = bv;

#pragma unroll
  for (int j = 0; j < TT_ + KW_ - 1; ++j) {
    int tj = t0 - 15 + j;
    float xv = ((unsigned)tj < (unsigned)T_) ? bf2f(xp[(size_t)tj * EC_]) : 0.f;
#pragma unroll
    for (int i = 0; i < TT_; ++i) {
      int k = j - i;
      if (k >= 0 && k < KW_) out[i] = fmaf(xv, wr[k], out[i]);
    }
  }
  float* yp = Y + ((size_t)b * T_ + t0) * EC_ + e;
#pragma unroll
  for (int i = 0; i < TT_; ++i) yp[(size_t)i * EC_] = out[i];
}

// ---------------------------------------------------------------- GroupNorm
__global__ __launch_bounds__(256) void gn_reduce_kernel(const float* __restrict__ X,
                                                        float* __restrict__ partial)
{
  int b = blockIdx.y, blk = blockIdx.x;
  const float* p = X + (size_t)b * (T_ * EC_) + (size_t)blk * 8192;
  int t = threadIdx.x;
  float s = 0.f, s2 = 0.f;
#pragma unroll
  for (int i = 0; i < 8; ++i) {
    float4 v = *(const float4*)(p + (size_t)((i << 8) + t) * 4);
    s  += v.x + v.y + v.z + v.w;
    s2 += v.x * v.x + v.y * v.y + v.z * v.z + v.w * v.w;
  }
#pragma unroll
  for (int off = 32; off; off >>= 1) {
    s  += __shfl_down(s,  off, 64);
    s2 += __shfl_down(s2, off, 64);
  }
  __shared__ float rs[4], rq[4];
  if ((t & 63) == 0) { rs[t >> 6] = s; rq[t >> 6] = s2; }
  __syncthreads();
  if (t == 0) {
    partial[(b * 128 + blk) * 2]     = rs[0] + rs[1] + rs[2] + rs[3];
    partial[(b * 128 + blk) * 2 + 1] = rq[0] + rq[1] + rq[2] + rq[3];
  }
}

__global__ __launch_bounds__(128) void gn_stats_kernel(const float* __restrict__ partial,
                                                       float* __restrict__ stats)
{
  int b = blockIdx.x, t = threadIdx.x;
  float s  = partial[(b * 128 + t) * 2];
  float s2 = partial[(b * 128 + t) * 2 + 1];
#pragma unroll
  for (int off = 32; off; off >>= 1) {
    s  += __shfl_down(s,  off, 64);
    s2 += __shfl_down(s2, off, 64);
  }
  __shared__ float rs[2], rq[2];
  if ((t & 63) == 0) { rs[t >> 6] = s; rq[t >> 6] = s2; }
  __syncthreads();
  if (t == 0) {
    float S = rs[0] + rs[1], S2 = rq[0] + rq[1];
    const float n = (float)(T_ * EC_);
    float mean = S / n;
    float var  = S2 / n - mean * mean;
    stats[b * 2]     = mean;
    stats[b * 2 + 1] = 1.0f / sqrtf(var + 1e-5f);
  }
}

__global__ __launch_bounds__(256) void gn_apply_kernel(const float* __restrict__ X,
    const float* __restrict__ stats, const float* __restrict__ g, const float* __restrict__ bb,
    unsigned short* __restrict__ out)
{
  int idx = blockIdx.x * 256 + threadIdx.x;
  int e4 = (idx & 255) << 2;
  int bt = idx >> 8;
  int b  = bt >> 10;
  float mean = stats[b * 2], rstd = stats[b * 2 + 1];
  float4 v  = *(const float4*)(X + (size_t)idx * 4);
  float4 gv = *(const float4*)(g + e4);
  float4 bv = *(const float4*)(bb + e4);
  float vv[4] = {v.x, v.y, v.z, v.w};
  float gg[4] = {gv.x, gv.y, gv.z, gv.w};
  float bbv[4] = {bv.x, bv.y, bv.z, bv.w};
  ushort4v o;
#pragma unroll
  for (int j = 0; j < 4; ++j) {
    float u = (vv[j] - mean) * rstd * gg[j] + bbv[j];
    o[j] = f2bf(u * (1.0f / (1.0f + __expf(-u))));
  }
  *(ushort4v*)(out + (size_t)idx * 4) = o;
}

// ---------------------------------------------------------------- launch
extern "C" void kernel_launch(void* const* d_in, const int* in_sizes, int n_in,
                              void* d_out, int out_size, void* d_ws, size_t ws_size,
                              hipStream_t stream)
{
  const float* in_x      = (const float*)d_in[0];
  const float* ffn1_ln_g = (const float*)d_in[1];
  const float* ffn1_ln_b = (const float*)d_in[2];
  const float* ffn1_w1   = (const float*)d_in[3];
  const float* ffn1_b1   = (const float*)d_in[4];
  const float* ffn1_w2   = (const float*)d_in[5];
  const float* ffn1_b2   = (const float*)d_in[6];
  const float* attn_ln_g = (const float*)d_in[7];
  const float* attn_ln_b = (const float*)d_in[8];
  const float* qkv_w     = (const float*)d_in[9];
  const float* qkv_b     = (const float*)d_in[10];
  const float* outp_w    = (const float*)d_in[11];
  const float* outp_b    = (const float*)d_in[12];
  const float* conv_ln_g = (const float*)d_in[13];
  const float* conv_ln_b = (const float*)d_in[14];
  const float* pw1_w     = (const float*)d_in[15];
  const float* pw1_b     = (const float*)d_in[16];
  const float* dw_w      = (const float*)d_in[17];
  const float* dw_b      = (const float*)d_in[18];
  const float* gn_g      = (const float*)d_in[19];
  const float* gn_b      = (const float*)d_in[20];
  const float* pw2_w     = (const float*)d_in[21];
  const float* pw2_b     = (const float*)d_in[22];
  const float* ffn2_ln_g = (const float*)d_in[23];
  const float* ffn2_ln_b = (const float*)d_in[24];
  const float* ffn2_w1   = (const float*)d_in[25];
  const float* ffn2_b1   = (const float*)d_in[26];
  const float* ffn2_w2   = (const float*)d_in[27];
  const float* ffn2_b2   = (const float*)d_in[28];
  const float* blk_ln_g  = (const float*)d_in[29];
  const float* blk_ln_b  = (const float*)d_in[30];
  const float* fin_ln_g  = (const float*)d_in[31];
  const float* fin_ln_b  = (const float*)d_in[32];

  char* p = (char*)d_ws;
  float* x    = (float*)p;          p += (size_t)ROWS * D_ * 4;
  float* big3 = (float*)p;          p += (size_t)ROWS * EC_ * 4;
  float* red  = (float*)p;          p += 4096 * 4;
  unsigned short* abuf  = (unsigned short*)p; p += (size_t)ROWS * D_ * 2;
  unsigned short* inner = (unsigned short*)p; p += (size_t)ROWS * FF_ * 2;
  unsigned short* big2  = (unsigned short*)p; p += (size_t)ROWS * EC_ * 2;
  unsigned short* wt_w1a = (unsigned short*)p; p += (size_t)L_ * D_ * FF_ * 2;
  unsigned short* wt_w1b = (unsigned short*)p; p += (size_t)L_ * FF_ * D_ * 2;
  unsigned short* wt_qkv = (unsigned short*)p; p += (size_t)L_ * D_ * 1536 * 2;
  unsigned short* wt_out = (unsigned short*)p; p += (size_t)L_ * D_ * D_ * 2;
  unsigned short* wt_pw1 = (unsigned short*)p; p += (size_t)L_ * D_ * 2048 * 2;
  unsigned short* wt_pw2 = (unsigned short*)p; p += (size_t)L_ * EC_ * D_ * 2;
  unsigned short* wt_w2a = (unsigned short*)p; p += (size_t)L_ * D_ * FF_ * 2;
  unsigned short* wt_w2b = (unsigned short*)p; p += (size_t)L_ * FF_ * D_ * 2;

  hipMemcpyAsync(x, in_x, sizeof(float) * (size_t)ROWS * D_,
                 hipMemcpyDeviceToDevice, stream);

  dim3 blk256(256);
  wtr_kernel<<<dim3(FF_/32,  D_/32,  L_), blk256, 0, stream>>>(ffn1_w1, wt_w1a, D_, FF_);
  wtr_kernel<<<dim3(D_/32,   FF_/32, L_), blk256, 0, stream>>>(ffn1_w2, wt_w1b, FF_, D_);
  wtr_kernel<<<dim3(1536/32, D_/32,  L_), blk256, 0, stream>>>(qkv_w,   wt_qkv, D_, 1536);
  wtr_kernel<<<dim3(D_/32,   D_/32,  L_), blk256, 0, stream>>>(outp_w,  wt_out, D_, D_);
  wtr_kernel<<<dim3(2048/32, D_/32,  L_), blk256, 0, stream>>>(pw1_w,   wt_pw1, D_, 2048);
  wtr_kernel<<<dim3(D_/32,   EC_/32, L_), blk256, 0, stream>>>(pw2_w,   wt_pw2, EC_, D_);
  wtr_kernel<<<dim3(FF_/32,  D_/32,  L_), blk256, 0, stream>>>(ffn2_w1, wt_w2a, D_, FF_);
  wtr_kernel<<<dim3(D_/32,   FF_/32, L_), blk256, 0, stream>>>(ffn2_w2, wt_w2b, FF_, D_);

  // first FFN1 LN (layer 0); subsequent ones are fused into the boundary dual-LN
  ln_bf16_kernel<<<ROWS, blk256, 0, stream>>>(x, ffn1_ln_g, ffn1_ln_b, abuf);

  for (int l = 0; l < L_; ++l) {
    // ---- FFN1 ----
    gemm_mfma<1><<<dim3(FF_/128, ROWS/128), blk256, 0, stream>>>(
        abuf, wt_w1a + (size_t)l*D_*FF_, ffn1_b1 + l*FF_, nullptr, inner, FF_, D_, 0.f);
    gemm_mfma<2><<<dim3(D_/128, ROWS/128), blk256, 0, stream>>>(
        inner, wt_w1b + (size_t)l*FF_*D_, ffn1_b2 + l*D_, x, x, D_, FF_, 0.5f);

    // ---- local windowed MHSA ----
    ln_bf16_kernel<<<ROWS, blk256, 0, stream>>>(x, attn_ln_g + l*D_, attn_ln_b + l*D_, abuf);
    gemm_mfma<0><<<dim3(1536/128, ROWS/128), blk256, 0, stream>>>(
        abuf, wt_qkv + (size_t)l*D_*1536, qkv_b + l*1536, nullptr, inner, 1536, D_, 0.f);
    attn_kernel<<<dim3(T_/64, H_, B_), blk256, 0, stream>>>(inner, abuf);
    gemm_mfma<2><<<dim3(D_/128, ROWS/128), blk256, 0, stream>>>(
        abuf, wt_out + (size_t)l*D_*D_, outp_b + l*D_, x, x, D_, D_, 1.0f);

    // ---- conv module ----
    ln_bf16_kernel<<<ROWS, blk256, 0, stream>>>(x, conv_ln_g + l*D_, conv_ln_b + l*D_, abuf);
    gemm_mfma<0><<<dim3(2048/128, ROWS/128), blk256, 0, stream>>>(
        abuf, wt_pw1 + (size_t)l*D_*2048, pw1_b + l*2048, nullptr, inner, 2048, D_, 0.f);
    glu_kernel<<<(ROWS * EC_ / 4) / 256, blk256, 0, stream>>>(inner, big2);
    dwconv_kernel<<<B_ * (T_/TT_) * (EC_/256), blk256, 0, stream>>>(
        big2, dw_w + (size_t)l*EC_*KW_, dw_b + l*EC_, big3);
    gn_reduce_kernel<<<dim3(128, B_), blk256, 0, stream>>>(big3, red);
    gn_stats_kernel<<<B_, 128, 0, stream>>>(red, red + 2048);
    gn_apply_kernel<<<(ROWS * EC_ / 4) / 256, blk256, 0, stream>>>(
        big3, red + 2048, gn_g + l*EC_, gn_b + l*EC_, big2);
    gemm_mfma<2><<<dim3(D_/128, ROWS/128), blk256, 0, stream>>>(
        big2, wt_pw2 + (size_t)l*EC_*D_, pw2_b + l*D_, x, x, D_, EC_, 1.0f);

    // ---- FFN2 ----
    ln_bf16_kernel<<<ROWS, blk256, 0, stream>>>(x, ffn2_ln_g + l*D_, ffn2_ln_b + l*D_, abuf);
    gemm_mfma<1><<<dim3(FF_/128, ROWS/128), blk256, 0, stream>>>(
        abuf, wt_w2a + (size_t)l*D_*FF_, ffn2_b1 + l*FF_, nullptr, inner, FF_, D_, 0.f);
    gemm_mfma<2><<<dim3(D_/128, ROWS/128), blk256, 0, stream>>>(
        inner, wt_w2b + (size_t)l*FF_*D_, ffn2_b2 + l*D_, x, x, D_, FF_, 0.5f);

    // ---- boundary: blk LN fused with next LN ----
    if (l < L_ - 1) {
      ln_dual_kernel<true><<<ROWS, blk256, 0, stream>>>(
          x, blk_ln_g + l*D_, blk_ln_b + l*D_,
          ffn1_ln_g + (l+1)*D_, ffn1_ln_b + (l+1)*D_, x, abuf);
    } else {
      ln_dual_kernel<false><<<ROWS, blk256, 0, stream>>>(
          x, blk_ln_g + l*D_, blk_ln_b + l*D_, fin_ln_g, fin_ln_b, x, d_out);
    }
  }
}